// Round 2
// baseline (1206.739 us; speedup 1.0000x reference)
//
#include <hip/hip_runtime.h>
#include <math.h>

#define DIMM 2048
#define D_INNER 4096
#define D_STATE 128
#define N_HEADS 32
#define CHUNK 256
#define CONV_DIM 4352
#define D_IN_PROJ 8480
#define BATCH 2
#define SEQ 2048
#define NTOK 4096
#define NCHUNK 8
#define HEADDIM 128
#define NXB 4480            // padded width of the xBC+dt GEMM1 output (35*128)

typedef short bf16x8 __attribute__((ext_vector_type(8)));
typedef float f32x4 __attribute__((ext_vector_type(4)));

__device__ __forceinline__ unsigned short f32_to_bf16(float f) {
    unsigned int u = __float_as_uint(f);
    unsigned int r = (u + 0x7FFFu + ((u >> 16) & 1u)) >> 16;
    return (unsigned short)r;
}
__device__ __forceinline__ float bf16_to_f32(unsigned short h) {
    return __uint_as_float(((unsigned int)h) << 16);
}
__device__ __forceinline__ float siluf(float v) { return v / (1.f + expf(-v)); }

// ---------------------------------------------------------------------------
// Generic batched bf16 GEMM:  C[m][n] = sum_k A[m][k] * W[n][k]  (+bias/scales)
// Both operands row-major, K contiguous. Tile 128x128, BK=64, 4 waves 2x2.
// z = (b*nc + c)*nh + h with per-dim strides (elements).
// kscale: multiplies A rows by kscale[k] during staging.
// nscale: multiplies result column n in epilogue.
// outbf: 0 = f32 output, 1 = bf16 output.  accum: 0 = store, 1 = +=.
// ---------------------------------------------------------------------------
__global__ __launch_bounds__(256)
void gemm_bt(const unsigned short* __restrict__ A, long lda, long sAb, long sAc, long sAh,
             const unsigned short* __restrict__ Wg, long ldw, long sWb, long sWc, long sWh,
             void* __restrict__ Cmv, long ldc, long sCb, long sCc, long sCh,
             int K, int nc, int nh,
             const float* __restrict__ bias, int bias_n,
             const float* __restrict__ kscale, long sKb, long sKc, long sKh,
             const float* __restrict__ nscale, long sNb, long sNc, long sNh,
             int accum, int outbf)
{
    __shared__ unsigned short As[128 * 64];
    __shared__ unsigned short Ws[128 * 64];

    const int tid = threadIdx.x;
    const int z = blockIdx.z;
    const int h = z % nh;
    const int zc = z / nh;
    const int c = zc % nc;
    const int b = zc / nc;

    const unsigned short* Ab = A + (size_t)(b * sAb + c * sAc + h * sAh);
    const unsigned short* Wb = Wg + (size_t)(b * sWb + c * sWc + h * sWh);
    const size_t coff = (size_t)(b * sCb + c * sCc + h * sCh);
    const float* ksb = kscale ? (kscale + (size_t)(b * sKb + c * sKc + h * sKh)) : nullptr;
    const float* nsb = nscale ? (nscale + (size_t)(b * sNb + c * sNc + h * sNh)) : nullptr;

    const long bm = (long)blockIdx.y * 128;
    const long bn = (long)blockIdx.x * 128;

    const int lane = tid & 63;
    const int wave = tid >> 6;
    const int wrow = (wave >> 1) * 64;
    const int wcol = (wave & 1) * 64;
    const int lr = lane & 15;
    const int quad = lane >> 4;

    f32x4 acc[4][4] = {};

    for (int k0 = 0; k0 < K; k0 += 64) {
        __syncthreads();
        #pragma unroll
        for (int q = 0; q < 4; ++q) {
            int cidx = tid + q * 256;          // 1024 chunks of 8 bf16 per tile
            int row = cidx >> 3;
            int cg = cidx & 7;
            int kk = k0 + cg * 8;
            uint4 va = *(const uint4*)(Ab + (bm + row) * lda + kk);
            if (ksb) {
                const float* ks = ksb + kk;
                unsigned int vv[4] = {va.x, va.y, va.z, va.w};
                #pragma unroll
                for (int e = 0; e < 4; ++e) {
                    float lo = __uint_as_float((vv[e] & 0xFFFFu) << 16) * ks[2 * e];
                    float hi = __uint_as_float(vv[e] & 0xFFFF0000u) * ks[2 * e + 1];
                    vv[e] = (unsigned int)f32_to_bf16(lo) | ((unsigned int)f32_to_bf16(hi) << 16);
                }
                va = make_uint4(vv[0], vv[1], vv[2], vv[3]);
            }
            *(uint4*)&As[row * 64 + cg * 8] = va;
            uint4 vw = *(const uint4*)(Wb + (bn + row) * ldw + kk);
            *(uint4*)&Ws[row * 64 + cg * 8] = vw;
        }
        __syncthreads();
        #pragma unroll
        for (int kk = 0; kk < 64; kk += 32) {
            bf16x8 av[4], bv[4];
            #pragma unroll
            for (int i = 0; i < 4; ++i)
                av[i] = *(const bf16x8*)&As[(wrow + i * 16 + lr) * 64 + kk + quad * 8];
            #pragma unroll
            for (int j = 0; j < 4; ++j)
                bv[j] = *(const bf16x8*)&Ws[(wcol + j * 16 + lr) * 64 + kk + quad * 8];
            #pragma unroll
            for (int i = 0; i < 4; ++i)
                #pragma unroll
                for (int j = 0; j < 4; ++j)
                    acc[i][j] = __builtin_amdgcn_mfma_f32_16x16x32_bf16(av[i], bv[j], acc[i][j], 0, 0, 0);
        }
    }

    #pragma unroll
    for (int i = 0; i < 4; ++i) {
        #pragma unroll
        for (int j = 0; j < 4; ++j) {
            #pragma unroll
            for (int r = 0; r < 4; ++r) {
                long row = bm + wrow + i * 16 + quad * 4 + r;
                long col = bn + wcol + j * 16 + lr;
                float v = acc[i][j][r];
                if (nsb) v *= nsb[col];
                if (bias && col < bias_n) v += bias[col];
                if (outbf) {
                    unsigned short* dst = (unsigned short*)Cmv + coff + row * ldc + col;
                    if (accum) v += bf16_to_f32(*dst);
                    *dst = f32_to_bf16(v);
                } else {
                    float* dst = (float*)Cmv + coff + row * ldc + col;
                    if (accum) *dst += v; else *dst = v;
                }
            }
        }
    }
}

// ---------------------------------------------------------------------------
__global__ __launch_bounds__(256)
void k_convert(const float* __restrict__ src, unsigned short* __restrict__ dst,
               long ncopy, long ntotal)
{
    long i = (long)blockIdx.x * 256 + threadIdx.x;
    long stride = (long)gridDim.x * 256;
    for (; i < ntotal; i += stride)
        dst[i] = (i < ncopy) ? f32_to_bf16(src[i]) : (unsigned short)0;
}

// dt = softplus(dt_raw + dt_bias) per (token, head); Zx is bf16 [NTOK][NXB]
__global__ __launch_bounds__(256)
void k_dt(const unsigned short* __restrict__ Zx, const float* __restrict__ dt_bias,
          float* __restrict__ dtv)
{
    int i = blockIdx.x * 256 + threadIdx.x;
    if (i >= NTOK * N_HEADS) return;
    int t = i >> 5, h = i & 31;
    float raw = bf16_to_f32(Zx[(size_t)t * NXB + CONV_DIM + h]) + dt_bias[h];
    dtv[i] = raw > 20.f ? raw : log1pf(expf(raw));
}

// per (b,c,h): inclusive cumsum of A*dt over l; decay tables
__global__ __launch_bounds__(256)
void k_cumsum(const float* __restrict__ dtv, const float* __restrict__ A_log,
              float* __restrict__ Acs, float* __restrict__ cdec,
              float* __restrict__ eacs, float* __restrict__ ctot)
{
    int z = blockIdx.x;                 // (b*8+c)*32 + h
    int h = z & 31, c = (z >> 5) & 7, b = z >> 8;
    int l = threadIdx.x;
    int t = ((b * 8 + c) << 8) + l;
    float dv = dtv[t * 32 + h];
    float a = -expf(A_log[h]) * dv;
    __shared__ float sb[256];
    sb[l] = a;
    __syncthreads();
    float v = a;
    for (int o = 1; o < 256; o <<= 1) {
        float add = (l >= o) ? sb[l - o] : 0.f;
        __syncthreads();
        v += add;
        sb[l] = v;
        __syncthreads();
    }
    float total = sb[255];
    Acs[(size_t)z * 256 + l] = v;
    cdec[(size_t)z * 256 + l] = expf(total - v) * dv;   // decay_states * dt
    eacs[(size_t)z * 256 + l] = expf(v);                // state_decay_out
    if (l == 255) ctot[(b * 32 + h) * 8 + c] = total;
}

// causal depthwise conv + silu over bf16 Zx; emits transposed bf16 copies
__global__ __launch_bounds__(256)
void k_conv(const unsigned short* __restrict__ Zx, const float* __restrict__ conv_w,
            const float* __restrict__ conv_b,
            unsigned short* __restrict__ Xt, unsigned short* __restrict__ Bbf,
            unsigned short* __restrict__ Cbf, unsigned short* __restrict__ Bt)
{
    int ch = blockIdx.x * 256 + threadIdx.x;
    if (ch >= CONV_DIM) return;
    int t = blockIdx.y;
    int b = t >> 11, s = t & 2047;
    float acc = conv_b[ch];
    #pragma unroll
    for (int k = 0; k < 4; ++k) {
        int ss = s - 3 + k;
        if (ss >= 0)
            acc += bf16_to_f32(Zx[(size_t)((b << 11) + ss) * NXB + ch]) * conv_w[ch * 4 + k];
    }
    acc = siluf(acc);
    unsigned short hb = f32_to_bf16(acc);
    if (ch < D_INNER) {
        int hh = ch >> 7, p = ch & 127;
        Xt[((size_t)(b * 32 + hh) * 128 + p) * 2048 + s] = hb;
    } else if (ch < D_INNER + D_STATE) {
        int n = ch - D_INNER;
        Bbf[(size_t)t * 128 + n] = hb;
        Bt[((size_t)(b * 128 + n)) * 2048 + s] = hb;
    } else {
        int n = ch - D_INNER - D_STATE;
        Cbf[(size_t)t * 128 + n] = hb;
    }
}

// Wbf[z-z_base][l][s] = (s<=l) * exp(Acs[l]-Acs[s]) * dt[s] * G[bc][l][s]
__global__ __launch_bounds__(256)
void k_wbuild(const float* __restrict__ Acs, const float* __restrict__ dtv,
              const float* __restrict__ G, unsigned short* __restrict__ Wbf,
              int z_base)
{
    int l = blockIdx.x;
    int zr = blockIdx.y;
    int z = z_base + zr;
    int s = threadIdx.x;
    int h = z & 31, c = (z >> 5) & 7, b = z >> 8;
    float w = 0.f;
    if (s <= l) {
        float e = expf(Acs[(size_t)z * 256 + l] - Acs[(size_t)z * 256 + s]);
        int t = ((b * 8 + c) << 8) + s;
        w = e * dtv[t * 32 + h] * G[(size_t)(b * 8 + c) * 65536 + l * 256 + s];
    }
    Wbf[(size_t)zr * 65536 + l * 256 + s] = f32_to_bf16(w);
}

// sequential 8-chunk state recurrence; writes incoming state (bf16) per chunk
__global__ __launch_bounds__(256)
void k_recur(const float* __restrict__ Sloc, const float* __restrict__ ctot,
             unsigned short* __restrict__ Sin)
{
    int i = blockIdx.x * 256 + threadIdx.x;    // over 2*32*128*128
    int n = i & 127, p = (i >> 7) & 127, h = (i >> 14) & 31, b = i >> 19;
    float s = 0.f;
    for (int c = 0; c < 8; ++c) {
        size_t idx = ((((size_t)(b * 8 + c) * 32 + h) * 128 + p) * 128 + n);
        Sin[idx] = f32_to_bf16(s);
        s = s * expf(ctot[(b * 32 + h) * 8 + c]) + Sloc[idx];
    }
}

// Y += D*x ; *= silu(z) ; RMSNorm*norm_w ; -> bf16 for out_proj
__global__ __launch_bounds__(256)
void k_combine(const unsigned short* __restrict__ Yt, const unsigned short* __restrict__ Xt,
               const unsigned short* __restrict__ Zz, const float* __restrict__ Dv,
               const float* __restrict__ norm_w, unsigned short* __restrict__ Ybf)
{
    int t = blockIdx.x;
    int b = t >> 11, s = t & 2047;
    int tid = threadIdx.x;
    float vals[16];
    float ss = 0.f;
    #pragma unroll
    for (int it = 0; it < 16; ++it) {
        int d = tid + it * 256;
        int hh = d >> 7, p = d & 127;
        size_t tix = ((size_t)(b * 32 + hh) * 128 + p) * 2048 + s;
        float yv = bf16_to_f32(Yt[tix]) + Dv[hh] * bf16_to_f32(Xt[tix]);
        float zv = bf16_to_f32(Zz[(size_t)t * 4096 + d]);
        yv *= siluf(zv);
        vals[it] = yv;
        ss += yv * yv;
    }
    #pragma unroll
    for (int o = 32; o > 0; o >>= 1) ss += __shfl_down(ss, o, 64);
    __shared__ float red[4];
    if ((tid & 63) == 0) red[tid >> 6] = ss;
    __syncthreads();
    float tot = red[0] + red[1] + red[2] + red[3];
    float scale = rsqrtf(tot / 4096.f + 1e-5f);
    #pragma unroll
    for (int it = 0; it < 16; ++it) {
        int d = tid + it * 256;
        Ybf[(size_t)t * 4096 + d] = f32_to_bf16(vals[it] * scale * norm_w[d]);
    }
}

// ---------------------------------------------------------------------------
extern "C" void kernel_launch(void* const* d_in, const int* in_sizes, int n_in,
                              void* d_out, int out_size, void* d_ws, size_t ws_size,
                              hipStream_t stream)
{
    if (n_in < 11) return;
    const float* inputs     = (const float*)d_in[0];
    const float* in_proj_w  = (const float*)d_in[1];
    const float* in_proj_b  = (const float*)d_in[2];
    const float* out_proj_w = (const float*)d_in[3];
    const float* out_proj_b = (const float*)d_in[4];
    const float* conv_w     = (const float*)d_in[5];
    const float* conv_b     = (const float*)d_in[6];
    const float* dt_bias    = (const float*)d_in[7];
    const float* A_log      = (const float*)d_in[8];
    const float* Dv         = (const float*)d_in[9];
    const float* norm_w     = (const float*)d_in[10];
    float* out = (float*)d_out;

    // ---- workspace plan (aliased regions; all sizes multiple of 256 B) ----
    char* base = (char*)d_ws;
    const size_t SZ_ABF  = (size_t)NTOK * DIMM * 2;            // 16.78 MB
    const size_t SZ_W1   = (size_t)8576 * DIMM * 2;            // 35.13 MB
    const size_t SZ_R0   = SZ_ABF + SZ_W1;                     // 51.90 MB
    const size_t SZ_ZZ   = (size_t)NTOK * 4096 * 2;            // 33.55 MB
    const size_t SZ_R3   = (size_t)NTOK * NXB * 2;             // 36.70 MB (>= Yt 33.55)
    const size_t SZ_XT   = (size_t)BATCH * 32 * 128 * 2048 * 2;// 33.55 MB
    const size_t SZ_R2   = (size_t)256 * 65536 * 2;            // 33.55 MB (Wbf stage / W2bf)
    size_t off = 0;
    char* R0   = base + off; off += SZ_R0;
    char* Zz   = base + off; off += SZ_ZZ;
    char* R3   = base + off; off += SZ_R3;
    char* XtB  = base + off; off += SZ_XT;
    char* R2   = base + off; off += SZ_R2;
    unsigned short* Bbf = (unsigned short*)(base + off); off += (size_t)NTOK * 128 * 2;
    unsigned short* Cbf = (unsigned short*)(base + off); off += (size_t)NTOK * 128 * 2;
    unsigned short* Bt  = (unsigned short*)(base + off); off += (size_t)BATCH * 128 * 2048 * 2;
    float* dtv  = (float*)(base + off); off += (size_t)NTOK * 32 * 4;
    float* Acs  = (float*)(base + off); off += (size_t)512 * 256 * 4;
    float* cdec = (float*)(base + off); off += (size_t)512 * 256 * 4;
    float* eacs = (float*)(base + off); off += (size_t)512 * 256 * 4;
    float* ctot = (float*)(base + off); off += (size_t)512 * 4;
    float* G    = (float*)(base + off); off += (size_t)16 * 65536 * 4;
    if (off > ws_size) return;   // ws too small (signature: absmax == max|ref|)

    unsigned short* Abf  = (unsigned short*)R0;                 // phase A
    unsigned short* W1bf = (unsigned short*)(R0 + SZ_ABF);      // phase A
    unsigned short* Sin  = (unsigned short*)R0;                 // after GEMM1
    unsigned short* Ybf  = (unsigned short*)(R0 + SZ_ABF);      // after Xt dead? no: after W1 dead
    unsigned short* Zzb  = (unsigned short*)Zz;                 // z-part, live till combine
    unsigned short* Zxb  = (unsigned short*)R3;                 // xBC+dt part, dead after conv
    unsigned short* Yt   = (unsigned short*)R3;                 // after conv
    unsigned short* Xt   = (unsigned short*)XtB;
    unsigned short* Wbf  = (unsigned short*)R2;                 // staged, 256 z at a time
    unsigned short* W2bf = (unsigned short*)R2;                 // after Y_diag stages
    float* Sloc = (float*)d_out;                                // 33.55 MB, exact fit

    // 1. converts
    k_convert<<<2048, 256, 0, stream>>>(inputs, Abf, (long)NTOK * DIMM, (long)NTOK * DIMM);
    k_convert<<<2048, 256, 0, stream>>>(in_proj_w, W1bf, (long)D_IN_PROJ * DIMM, (long)8576 * DIMM);

    // 2a. GEMM1 z-part: Zzb[4096][4096] = Abf @ W1[0:4096]^T + b  (bf16 out)
    gemm_bt<<<dim3(32, 32, 1), 256, 0, stream>>>(
        Abf, DIMM, 0, 0, 0,  W1bf, DIMM, 0, 0, 0,
        Zzb, 4096, 0, 0, 0,  DIMM, 1, 1,
        in_proj_b, 4096,  nullptr, 0, 0, 0,  nullptr, 0, 0, 0,  0, 1);
    // 2b. GEMM1 xBC+dt part: Zxb[4096][4480] = Abf @ W1[4096:8576]^T + b
    gemm_bt<<<dim3(35, 32, 1), 256, 0, stream>>>(
        Abf, DIMM, 0, 0, 0,  W1bf + (size_t)4096 * DIMM, DIMM, 0, 0, 0,
        Zxb, NXB, 0, 0, 0,  DIMM, 1, 1,
        in_proj_b + 4096, D_IN_PROJ - 4096,  nullptr, 0, 0, 0,  nullptr, 0, 0, 0,  0, 1);

    // 3. dt + cumsum tables
    k_dt<<<(NTOK * N_HEADS) / 256, 256, 0, stream>>>(Zxb, dt_bias, dtv);
    k_cumsum<<<512, 256, 0, stream>>>(dtv, A_log, Acs, cdec, eacs, ctot);

    // 4. conv + silu + transposed bf16 splits
    k_conv<<<dim3(CONV_DIM / 256, NTOK, 1), 256, 0, stream>>>(Zxb, conv_w, conv_b, Xt, Bbf, Cbf, Bt);

    // 5. G = C @ B^T per (b,c):  M=256(l) N=256(s) K=128  (f32 out)
    gemm_bt<<<dim3(2, 2, 16), 256, 0, stream>>>(
        Cbf, 128, 2048L * 128, 256L * 128, 0,
        Bbf, 128, 2048L * 128, 256L * 128, 0,
        G, 256, 8L * 65536, 65536, 0,
        128, 8, 1,
        nullptr, 0, nullptr, 0, 0, 0, nullptr, 0, 0, 0, 0, 0);

    // 6/7. two stages (= batch b): build Wbf then Y_diag^T = Xt @ Wbf^T (bf16 out)
    for (int s = 0; s < 2; ++s) {
        k_wbuild<<<dim3(256, 256, 1), 256, 0, stream>>>(Acs, dtv, G, Wbf, s * 256);
        gemm_bt<<<dim3(2, 1, 256), 256, 0, stream>>>(
            Xt + (size_t)s * 32 * 128 * 2048, 2048, 0, 256, 128L * 2048,
            Wbf, 256, 0, 32L * 65536, 65536,
            Yt + (size_t)s * 32 * 128 * 2048, 2048, 0, 256, 128L * 2048,
            256, 8, 32,
            nullptr, 0, nullptr, 0, 0, 0, nullptr, 0, 0, 0, 0, 1);
    }

    // 8. local states[p][n] = (Xt * cdec) @ Bt^T  (f32 out into d_out scratch)
    gemm_bt<<<dim3(1, 1, 512), 256, 0, stream>>>(
        Xt, 2048, 32L * 128 * 2048, 256, 128L * 2048,
        Bt, 2048, 128L * 2048, 256, 0,
        Sloc, 128, 8L * 32 * 16384, 32L * 16384, 16384,
        256, 8, 32,
        nullptr, 0,
        cdec, 8L * 32 * 256, 32L * 256, 256,
        nullptr, 0, 0, 0, 0, 0);

    // 9. chunk recurrence -> incoming states (bf16)
    k_recur<<<4096, 256, 0, stream>>>(Sloc, ctot, Sin);

    // 10. Y_off^T = Sin @ Cbf^T, col-scaled by exp(Acs[l]), accum into bf16 Yt
    gemm_bt<<<dim3(2, 1, 512), 256, 0, stream>>>(
        Sin, 128, 8L * 32 * 16384, 32L * 16384, 16384,
        Cbf, 128, 2048L * 128, 256L * 128, 0,
        Yt, 2048, 32L * 128 * 2048, 256, 128L * 2048,
        128, 8, 32,
        nullptr, 0,
        nullptr, 0, 0, 0,
        eacs, 8L * 32 * 256, 32L * 256, 256,
        1, 1);

    // 11. out_proj weight convert (into dead Wbf region)
    k_convert<<<2048, 256, 0, stream>>>(out_proj_w, W2bf, (long)DIMM * D_INNER, (long)DIMM * D_INNER);

    // 12. combine: +D*x, *silu(z), RMSNorm -> Ybf (into dead W1bf region)
    k_combine<<<NTOK, 256, 0, stream>>>(Yt, Xt, Zzb, Dv, norm_w, Ybf);

    // 13. GEMM2: out[4096][2048] = Ybf @ W2bf^T + out_proj_b  (f32 out)
    gemm_bt<<<dim3(16, 32, 1), 256, 0, stream>>>(
        Ybf, D_INNER, 0, 0, 0,
        W2bf, D_INNER, 0, 0, 0,
        out, DIMM, 0, 0, 0,
        D_INNER, 1, 1,
        out_proj_b, DIMM,
        nullptr, 0, 0, 0, nullptr, 0, 0, 0, 0, 0);
}

// Round 3
// 1007.641 us; speedup vs baseline: 1.1976x; 1.1976x over previous
//
#include <hip/hip_runtime.h>
#include <math.h>

#define DIMM 2048
#define D_INNER 4096
#define D_STATE 128
#define N_HEADS 32
#define CHUNK 256
#define CONV_DIM 4352
#define D_IN_PROJ 8480
#define BATCH 2
#define SEQ 2048
#define NTOK 4096
#define NCHUNK 8
#define HEADDIM 128
#define NXB 4480            // padded width of the xBC+dt GEMM1 output (35*128)

typedef short bf16x8 __attribute__((ext_vector_type(8)));
typedef float f32x4 __attribute__((ext_vector_type(4)));

__device__ __forceinline__ unsigned short f32_to_bf16(float f) {
    unsigned int u = __float_as_uint(f);
    unsigned int r = (u + 0x7FFFu + ((u >> 16) & 1u)) >> 16;
    return (unsigned short)r;
}
__device__ __forceinline__ float bf16_to_f32(unsigned short h) {
    return __uint_as_float(((unsigned int)h) << 16);
}
__device__ __forceinline__ float siluf(float v) { return v / (1.f + expf(-v)); }

// async global->LDS DMA, 16 bytes per lane. LDS dest must be uniform+lane*16.
__device__ __forceinline__ void gload_lds16(const unsigned short* g, unsigned short* l) {
    __builtin_amdgcn_global_load_lds(
        (const __attribute__((address_space(1))) unsigned int*)((const void*)g),
        (__attribute__((address_space(3))) unsigned int*)((void*)l),
        16, 0, 0);
}

// ---------------------------------------------------------------------------
// Generic batched bf16 GEMM:  C[m][n] = sum_k A[m][k] * W[n][k]  (+bias/scales)
// Both operands row-major, K contiguous. Tile 128x128, BK=64, 4 waves 2x2.
// LDS tiles XOR-swizzled: slot (row, s) holds global k-chunk (s ^ (row&7)).
// Staging via global_load_lds (width 16); kscale path falls back to VALU.
// ---------------------------------------------------------------------------
__global__ __launch_bounds__(256)
void gemm_bt(const unsigned short* __restrict__ A, long lda, long sAb, long sAc, long sAh,
             const unsigned short* __restrict__ Wg, long ldw, long sWb, long sWc, long sWh,
             void* __restrict__ Cmv, long ldc, long sCb, long sCc, long sCh,
             int K, int nc, int nh,
             const float* __restrict__ bias, int bias_n,
             const float* __restrict__ kscale, long sKb, long sKc, long sKh,
             const float* __restrict__ nscale, long sNb, long sNc, long sNh,
             int accum, int outbf)
{
    __shared__ unsigned short As[128 * 64];
    __shared__ unsigned short Ws[128 * 64];

    const int tid = threadIdx.x;
    const int z = blockIdx.z;
    const int h = z % nh;
    const int zc = z / nh;
    const int c = zc % nc;
    const int b = zc / nc;

    const unsigned short* Ab = A + (size_t)(b * sAb + c * sAc + h * sAh);
    const unsigned short* Wb = Wg + (size_t)(b * sWb + c * sWc + h * sWh);
    const size_t coff = (size_t)(b * sCb + c * sCc + h * sCh);
    const float* ksb = kscale ? (kscale + (size_t)(b * sKb + c * sKc + h * sKh)) : nullptr;
    const float* nsb = nscale ? (nscale + (size_t)(b * sNb + c * sNc + h * sNh)) : nullptr;

    const long bm = (long)blockIdx.y * 128;
    const long bn = (long)blockIdx.x * 128;

    const int lane = tid & 63;
    const int wave = tid >> 6;
    const int wrow = (wave >> 1) * 64;
    const int wcol = (wave & 1) * 64;
    const int lr = lane & 15;
    const int quad = lane >> 4;

    f32x4 acc[4][4] = {};

    for (int k0 = 0; k0 < K; k0 += 64) {
        __syncthreads();
        if (!ksb) {
            #pragma unroll
            for (int q = 0; q < 4; ++q) {
                int cidx = tid + q * 256;      // LDS slot index (16B granules)
                int row = cidx >> 3;
                int sl = cidx & 7;
                int cg = sl ^ (row & 7);       // which global k-chunk this slot holds
                gload_lds16(Ab + (bm + row) * lda + k0 + cg * 8, &As[cidx * 8]);
                gload_lds16(Wb + (bn + row) * ldw + k0 + cg * 8, &Ws[cidx * 8]);
            }
        } else {
            #pragma unroll
            for (int q = 0; q < 4; ++q) {
                int cidx = tid + q * 256;
                int row = cidx >> 3;
                int sl = cidx & 7;
                int cg = sl ^ (row & 7);
                int kk = k0 + cg * 8;
                uint4 va = *(const uint4*)(Ab + (bm + row) * lda + kk);
                const float* ks = ksb + kk;
                unsigned int vv[4] = {va.x, va.y, va.z, va.w};
                #pragma unroll
                for (int e = 0; e < 4; ++e) {
                    float lo = __uint_as_float((vv[e] & 0xFFFFu) << 16) * ks[2 * e];
                    float hi = __uint_as_float(vv[e] & 0xFFFF0000u) * ks[2 * e + 1];
                    vv[e] = (unsigned int)f32_to_bf16(lo) | ((unsigned int)f32_to_bf16(hi) << 16);
                }
                *(uint4*)&As[cidx * 8] = make_uint4(vv[0], vv[1], vv[2], vv[3]);
                uint4 vw = *(const uint4*)(Wb + (bn + row) * ldw + kk);
                *(uint4*)&Ws[cidx * 8] = vw;
            }
        }
        __syncthreads();
        #pragma unroll
        for (int kk = 0; kk < 64; kk += 32) {
            const int cb = (kk >> 3) + quad;   // k-chunk this quad consumes
            bf16x8 av[4], bv[4];
            #pragma unroll
            for (int i = 0; i < 4; ++i) {
                int row = wrow + i * 16 + lr;
                av[i] = *(const bf16x8*)&As[row * 64 + ((cb ^ (row & 7)) * 8)];
            }
            #pragma unroll
            for (int j = 0; j < 4; ++j) {
                int row = wcol + j * 16 + lr;
                bv[j] = *(const bf16x8*)&Ws[row * 64 + ((cb ^ (row & 7)) * 8)];
            }
            #pragma unroll
            for (int i = 0; i < 4; ++i)
                #pragma unroll
                for (int j = 0; j < 4; ++j)
                    acc[i][j] = __builtin_amdgcn_mfma_f32_16x16x32_bf16(av[i], bv[j], acc[i][j], 0, 0, 0);
        }
    }

    #pragma unroll
    for (int i = 0; i < 4; ++i) {
        #pragma unroll
        for (int j = 0; j < 4; ++j) {
            #pragma unroll
            for (int r = 0; r < 4; ++r) {
                long row = bm + wrow + i * 16 + quad * 4 + r;
                long col = bn + wcol + j * 16 + lr;
                float v = acc[i][j][r];
                if (nsb) v *= nsb[col];
                if (bias && col < bias_n) v += bias[col];
                if (outbf) {
                    unsigned short* dst = (unsigned short*)Cmv + coff + row * ldc + col;
                    if (accum) v += bf16_to_f32(*dst);
                    *dst = f32_to_bf16(v);
                } else {
                    float* dst = (float*)Cmv + coff + row * ldc + col;
                    if (accum) *dst += v; else *dst = v;
                }
            }
        }
    }
}

// ---------------------------------------------------------------------------
__global__ __launch_bounds__(256)
void k_convert(const float* __restrict__ src, unsigned short* __restrict__ dst,
               long ncopy, long ntotal)
{
    long i = (long)blockIdx.x * 256 + threadIdx.x;
    long stride = (long)gridDim.x * 256;
    for (; i < ntotal; i += stride)
        dst[i] = (i < ncopy) ? f32_to_bf16(src[i]) : (unsigned short)0;
}

// dt = softplus(dt_raw + dt_bias) per (token, head); Zx is bf16 [NTOK][NXB]
__global__ __launch_bounds__(256)
void k_dt(const unsigned short* __restrict__ Zx, const float* __restrict__ dt_bias,
          float* __restrict__ dtv)
{
    int i = blockIdx.x * 256 + threadIdx.x;
    if (i >= NTOK * N_HEADS) return;
    int t = i >> 5, h = i & 31;
    float raw = bf16_to_f32(Zx[(size_t)t * NXB + CONV_DIM + h]) + dt_bias[h];
    dtv[i] = raw > 20.f ? raw : log1pf(expf(raw));
}

// per (b,c,h): inclusive cumsum of A*dt over l; decay tables
__global__ __launch_bounds__(256)
void k_cumsum(const float* __restrict__ dtv, const float* __restrict__ A_log,
              float* __restrict__ Acs, float* __restrict__ cdec,
              float* __restrict__ eacs, float* __restrict__ ctot)
{
    int z = blockIdx.x;                 // (b*8+c)*32 + h
    int h = z & 31, c = (z >> 5) & 7, b = z >> 8;
    int l = threadIdx.x;
    int t = ((b * 8 + c) << 8) + l;
    float dv = dtv[t * 32 + h];
    float a = -expf(A_log[h]) * dv;
    __shared__ float sb[256];
    sb[l] = a;
    __syncthreads();
    float v = a;
    for (int o = 1; o < 256; o <<= 1) {
        float add = (l >= o) ? sb[l - o] : 0.f;
        __syncthreads();
        v += add;
        sb[l] = v;
        __syncthreads();
    }
    float total = sb[255];
    Acs[(size_t)z * 256 + l] = v;
    cdec[(size_t)z * 256 + l] = expf(total - v) * dv;   // decay_states * dt
    eacs[(size_t)z * 256 + l] = expf(v);                // state_decay_out
    if (l == 255) ctot[(b * 32 + h) * 8 + c] = total;
}

// causal depthwise conv + silu over bf16 Zx; emits transposed bf16 copies
__global__ __launch_bounds__(256)
void k_conv(const unsigned short* __restrict__ Zx, const float* __restrict__ conv_w,
            const float* __restrict__ conv_b,
            unsigned short* __restrict__ Xt, unsigned short* __restrict__ Bbf,
            unsigned short* __restrict__ Cbf, unsigned short* __restrict__ Bt)
{
    int ch = blockIdx.x * 256 + threadIdx.x;
    if (ch >= CONV_DIM) return;
    int t = blockIdx.y;
    int b = t >> 11, s = t & 2047;
    float acc = conv_b[ch];
    #pragma unroll
    for (int k = 0; k < 4; ++k) {
        int ss = s - 3 + k;
        if (ss >= 0)
            acc += bf16_to_f32(Zx[(size_t)((b << 11) + ss) * NXB + ch]) * conv_w[ch * 4 + k];
    }
    acc = siluf(acc);
    unsigned short hb = f32_to_bf16(acc);
    if (ch < D_INNER) {
        int hh = ch >> 7, p = ch & 127;
        Xt[((size_t)(b * 32 + hh) * 128 + p) * 2048 + s] = hb;
    } else if (ch < D_INNER + D_STATE) {
        int n = ch - D_INNER;
        Bbf[(size_t)t * 128 + n] = hb;
        Bt[((size_t)(b * 128 + n)) * 2048 + s] = hb;
    } else {
        int n = ch - D_INNER - D_STATE;
        Cbf[(size_t)t * 128 + n] = hb;
    }
}

// Wbf[z-z_base][l][s] = (s<=l) * exp(Acs[l]-Acs[s]) * dt[s] * G[bc][l][s]
__global__ __launch_bounds__(256)
void k_wbuild(const float* __restrict__ Acs, const float* __restrict__ dtv,
              const float* __restrict__ G, unsigned short* __restrict__ Wbf,
              int z_base)
{
    int l = blockIdx.x;
    int zr = blockIdx.y;
    int z = z_base + zr;
    int s = threadIdx.x;
    int h = z & 31, c = (z >> 5) & 7, b = z >> 8;
    float w = 0.f;
    if (s <= l) {
        float e = expf(Acs[(size_t)z * 256 + l] - Acs[(size_t)z * 256 + s]);
        int t = ((b * 8 + c) << 8) + s;
        w = e * dtv[t * 32 + h] * G[(size_t)(b * 8 + c) * 65536 + l * 256 + s];
    }
    Wbf[(size_t)zr * 65536 + l * 256 + s] = f32_to_bf16(w);
}

// sequential 8-chunk state recurrence; writes incoming state (bf16) per chunk
__global__ __launch_bounds__(256)
void k_recur(const float* __restrict__ Sloc, const float* __restrict__ ctot,
             unsigned short* __restrict__ Sin)
{
    int i = blockIdx.x * 256 + threadIdx.x;    // over 2*32*128*128
    int n = i & 127, p = (i >> 7) & 127, h = (i >> 14) & 31, b = i >> 19;
    float s = 0.f;
    for (int c = 0; c < 8; ++c) {
        size_t idx = ((((size_t)(b * 8 + c) * 32 + h) * 128 + p) * 128 + n);
        Sin[idx] = f32_to_bf16(s);
        s = s * expf(ctot[(b * 32 + h) * 8 + c]) + Sloc[idx];
    }
}

// Y += D*x ; *= silu(z) ; RMSNorm*norm_w ; -> bf16 for out_proj
__global__ __launch_bounds__(256)
void k_combine(const unsigned short* __restrict__ Yt, const unsigned short* __restrict__ Xt,
               const unsigned short* __restrict__ Zz, const float* __restrict__ Dv,
               const float* __restrict__ norm_w, unsigned short* __restrict__ Ybf)
{
    int t = blockIdx.x;
    int b = t >> 11, s = t & 2047;
    int tid = threadIdx.x;
    float vals[16];
    float ss = 0.f;
    #pragma unroll
    for (int it = 0; it < 16; ++it) {
        int d = tid + it * 256;
        int hh = d >> 7, p = d & 127;
        size_t tix = ((size_t)(b * 32 + hh) * 128 + p) * 2048 + s;
        float yv = bf16_to_f32(Yt[tix]) + Dv[hh] * bf16_to_f32(Xt[tix]);
        float zv = bf16_to_f32(Zz[(size_t)t * 4096 + d]);
        yv *= siluf(zv);
        vals[it] = yv;
        ss += yv * yv;
    }
    #pragma unroll
    for (int o = 32; o > 0; o >>= 1) ss += __shfl_down(ss, o, 64);
    __shared__ float red[4];
    if ((tid & 63) == 0) red[tid >> 6] = ss;
    __syncthreads();
    float tot = red[0] + red[1] + red[2] + red[3];
    float scale = rsqrtf(tot / 4096.f + 1e-5f);
    #pragma unroll
    for (int it = 0; it < 16; ++it) {
        int d = tid + it * 256;
        Ybf[(size_t)t * 4096 + d] = f32_to_bf16(vals[it] * scale * norm_w[d]);
    }
}

// ---------------------------------------------------------------------------
extern "C" void kernel_launch(void* const* d_in, const int* in_sizes, int n_in,
                              void* d_out, int out_size, void* d_ws, size_t ws_size,
                              hipStream_t stream)
{
    if (n_in < 11) return;
    const float* inputs     = (const float*)d_in[0];
    const float* in_proj_w  = (const float*)d_in[1];
    const float* in_proj_b  = (const float*)d_in[2];
    const float* out_proj_w = (const float*)d_in[3];
    const float* out_proj_b = (const float*)d_in[4];
    const float* conv_w     = (const float*)d_in[5];
    const float* conv_b     = (const float*)d_in[6];
    const float* dt_bias    = (const float*)d_in[7];
    const float* A_log      = (const float*)d_in[8];
    const float* Dv         = (const float*)d_in[9];
    const float* norm_w     = (const float*)d_in[10];
    float* out = (float*)d_out;

    // ---- workspace plan (aliased regions; all sizes multiple of 256 B) ----
    char* base = (char*)d_ws;
    const size_t SZ_ABF  = (size_t)NTOK * DIMM * 2;            // 16.78 MB
    const size_t SZ_W1   = (size_t)8576 * DIMM * 2;            // 35.13 MB
    const size_t SZ_R0   = SZ_ABF + SZ_W1;                     // 51.90 MB
    const size_t SZ_ZZ   = (size_t)NTOK * 4096 * 2;            // 33.55 MB
    const size_t SZ_R3   = (size_t)NTOK * NXB * 2;             // 36.70 MB (>= Yt 33.55)
    const size_t SZ_XT   = (size_t)BATCH * 32 * 128 * 2048 * 2;// 33.55 MB
    const size_t SZ_R2   = (size_t)256 * 65536 * 2;            // 33.55 MB (Wbf stage / W2bf)
    size_t off = 0;
    char* R0   = base + off; off += SZ_R0;
    char* Zz   = base + off; off += SZ_ZZ;
    char* R3   = base + off; off += SZ_R3;
    char* XtB  = base + off; off += SZ_XT;
    char* R2   = base + off; off += SZ_R2;
    unsigned short* Bbf = (unsigned short*)(base + off); off += (size_t)NTOK * 128 * 2;
    unsigned short* Cbf = (unsigned short*)(base + off); off += (size_t)NTOK * 128 * 2;
    unsigned short* Bt  = (unsigned short*)(base + off); off += (size_t)BATCH * 128 * 2048 * 2;
    float* dtv  = (float*)(base + off); off += (size_t)NTOK * 32 * 4;
    float* Acs  = (float*)(base + off); off += (size_t)512 * 256 * 4;
    float* cdec = (float*)(base + off); off += (size_t)512 * 256 * 4;
    float* eacs = (float*)(base + off); off += (size_t)512 * 256 * 4;
    float* ctot = (float*)(base + off); off += (size_t)512 * 4;
    float* G    = (float*)(base + off); off += (size_t)16 * 65536 * 4;
    if (off > ws_size) return;   // ws too small (signature: absmax == max|ref|)

    unsigned short* Abf  = (unsigned short*)R0;                 // phase A
    unsigned short* W1bf = (unsigned short*)(R0 + SZ_ABF);      // phase A
    unsigned short* Sin  = (unsigned short*)R0;                 // after GEMM1
    unsigned short* Ybf  = (unsigned short*)(R0 + SZ_ABF);      // after W1 dead
    unsigned short* Zzb  = (unsigned short*)Zz;                 // z-part, live till combine
    unsigned short* Zxb  = (unsigned short*)R3;                 // xBC+dt part, dead after conv
    unsigned short* Yt   = (unsigned short*)R3;                 // after conv
    unsigned short* Xt   = (unsigned short*)XtB;
    unsigned short* Wbf  = (unsigned short*)R2;                 // staged, 256 z at a time
    unsigned short* W2bf = (unsigned short*)R2;                 // after Y_diag stages
    float* Sloc = (float*)d_out;                                // 33.55 MB, exact fit

    // 1. converts
    k_convert<<<2048, 256, 0, stream>>>(inputs, Abf, (long)NTOK * DIMM, (long)NTOK * DIMM);
    k_convert<<<2048, 256, 0, stream>>>(in_proj_w, W1bf, (long)D_IN_PROJ * DIMM, (long)8576 * DIMM);

    // 2a. GEMM1 z-part: Zzb[4096][4096] = Abf @ W1[0:4096]^T + b  (bf16 out)
    gemm_bt<<<dim3(32, 32, 1), 256, 0, stream>>>(
        Abf, DIMM, 0, 0, 0,  W1bf, DIMM, 0, 0, 0,
        Zzb, 4096, 0, 0, 0,  DIMM, 1, 1,
        in_proj_b, 4096,  nullptr, 0, 0, 0,  nullptr, 0, 0, 0,  0, 1);
    // 2b. GEMM1 xBC+dt part: Zxb[4096][4480] = Abf @ W1[4096:8576]^T + b
    gemm_bt<<<dim3(35, 32, 1), 256, 0, stream>>>(
        Abf, DIMM, 0, 0, 0,  W1bf + (size_t)4096 * DIMM, DIMM, 0, 0, 0,
        Zxb, NXB, 0, 0, 0,  DIMM, 1, 1,
        in_proj_b + 4096, D_IN_PROJ - 4096,  nullptr, 0, 0, 0,  nullptr, 0, 0, 0,  0, 1);

    // 3. dt + cumsum tables
    k_dt<<<(NTOK * N_HEADS) / 256, 256, 0, stream>>>(Zxb, dt_bias, dtv);
    k_cumsum<<<512, 256, 0, stream>>>(dtv, A_log, Acs, cdec, eacs, ctot);

    // 4. conv + silu + transposed bf16 splits
    k_conv<<<dim3(CONV_DIM / 256, NTOK, 1), 256, 0, stream>>>(Zxb, conv_w, conv_b, Xt, Bbf, Cbf, Bt);

    // 5. G = C @ B^T per (b,c):  M=256(l) N=256(s) K=128  (f32 out)
    gemm_bt<<<dim3(2, 2, 16), 256, 0, stream>>>(
        Cbf, 128, 2048L * 128, 256L * 128, 0,
        Bbf, 128, 2048L * 128, 256L * 128, 0,
        G, 256, 8L * 65536, 65536, 0,
        128, 8, 1,
        nullptr, 0, nullptr, 0, 0, 0, nullptr, 0, 0, 0, 0, 0);

    // 6/7. two stages (= batch b): build Wbf then Y_diag^T = Xt @ Wbf^T (bf16 out)
    for (int s = 0; s < 2; ++s) {
        k_wbuild<<<dim3(256, 256, 1), 256, 0, stream>>>(Acs, dtv, G, Wbf, s * 256);
        gemm_bt<<<dim3(2, 1, 256), 256, 0, stream>>>(
            Xt + (size_t)s * 32 * 128 * 2048, 2048, 0, 256, 128L * 2048,
            Wbf, 256, 0, 32L * 65536, 65536,
            Yt + (size_t)s * 32 * 128 * 2048, 2048, 0, 256, 128L * 2048,
            256, 8, 32,
            nullptr, 0, nullptr, 0, 0, 0, nullptr, 0, 0, 0, 0, 1);
    }

    // 8. local states[p][n] = (Xt * cdec) @ Bt^T  (f32 out into d_out scratch)
    gemm_bt<<<dim3(1, 1, 512), 256, 0, stream>>>(
        Xt, 2048, 32L * 128 * 2048, 256, 128L * 2048,
        Bt, 2048, 128L * 2048, 256, 0,
        Sloc, 128, 8L * 32 * 16384, 32L * 16384, 16384,
        256, 8, 32,
        nullptr, 0,
        cdec, 8L * 32 * 256, 32L * 256, 256,
        nullptr, 0, 0, 0, 0, 0);

    // 9. chunk recurrence -> incoming states (bf16)
    k_recur<<<4096, 256, 0, stream>>>(Sloc, ctot, Sin);

    // 10. Y_off^T = Sin @ Cbf^T, col-scaled by exp(Acs[l]), accum into bf16 Yt
    gemm_bt<<<dim3(2, 1, 512), 256, 0, stream>>>(
        Sin, 128, 8L * 32 * 16384, 32L * 16384, 16384,
        Cbf, 128, 2048L * 128, 256L * 128, 0,
        Yt, 2048, 32L * 128 * 2048, 256, 128L * 2048,
        128, 8, 32,
        nullptr, 0,
        nullptr, 0, 0, 0,
        eacs, 8L * 32 * 256, 32L * 256, 256,
        1, 1);

    // 11. out_proj weight convert (into dead Wbf region)
    k_convert<<<2048, 256, 0, stream>>>(out_proj_w, W2bf, (long)DIMM * D_INNER, (long)DIMM * D_INNER);

    // 12. combine: +D*x, *silu(z), RMSNorm -> Ybf (into dead W1bf region)
    k_combine<<<NTOK, 256, 0, stream>>>(Yt, Xt, Zzb, Dv, norm_w, Ybf);

    // 13. GEMM2: out[4096][2048] = Ybf @ W2bf^T + out_proj_b  (f32 out)
    gemm_bt<<<dim3(16, 32, 1), 256, 0, stream>>>(
        Ybf, D_INNER, 0, 0, 0,
        W2bf, D_INNER, 0, 0, 0,
        out, DIMM, 0, 0, 0,
        D_INNER, 1, 1,
        out_proj_b, DIMM,
        nullptr, 0, 0, 0, nullptr, 0, 0, 0, 0, 0);
}

// Round 4
// 775.190 us; speedup vs baseline: 1.5567x; 1.2999x over previous
//
#include <hip/hip_runtime.h>
#include <math.h>

#define DIMM 2048
#define D_INNER 4096
#define D_STATE 128
#define N_HEADS 32
#define CHUNK 256
#define CONV_DIM 4352
#define D_IN_PROJ 8480
#define BATCH 2
#define SEQ 2048
#define NTOK 4096
#define NCHUNK 8
#define HEADDIM 128
#define NXB 4480            // padded width of the xBC+dt GEMM1 output (35*128)

typedef short bf16x8 __attribute__((ext_vector_type(8)));
typedef float f32x4 __attribute__((ext_vector_type(4)));

__device__ __forceinline__ unsigned short f32_to_bf16(float f) {
    unsigned int u = __float_as_uint(f);
    unsigned int r = (u + 0x7FFFu + ((u >> 16) & 1u)) >> 16;
    return (unsigned short)r;
}
__device__ __forceinline__ float bf16_to_f32(unsigned short h) {
    return __uint_as_float(((unsigned int)h) << 16);
}
__device__ __forceinline__ float siluf(float v) { return v / (1.f + expf(-v)); }

// async global->LDS DMA, 16 bytes per lane. LDS dest must be uniform+lane*16.
__device__ __forceinline__ void gload_lds16(const unsigned short* g, unsigned short* l) {
    __builtin_amdgcn_global_load_lds(
        (const __attribute__((address_space(1))) unsigned int*)((const void*)g),
        (__attribute__((address_space(3))) unsigned int*)((void*)l),
        16, 0, 0);
}

// ---------------------------------------------------------------------------
// Generic batched bf16 GEMM:  C[m][n] = sum_k A[m][k] * W[n][k]  (+bias/scales)
// Both operands row-major, K contiguous. Tile 128x128, BK=64, 4 waves 2x2.
// LDS tiles XOR-swizzled: slot (row, s) holds global k-chunk (s ^ (row&7)).
// Staging via global_load_lds (width 16); kscale path falls back to VALU.
// kscale: A[m][k] *= kscale[k].  nscale: col scale.  mscale: row scale.
// ---------------------------------------------------------------------------
__global__ __launch_bounds__(256)
void gemm_bt(const unsigned short* __restrict__ A, long lda, long sAb, long sAc, long sAh,
             const unsigned short* __restrict__ Wg, long ldw, long sWb, long sWc, long sWh,
             void* __restrict__ Cmv, long ldc, long sCb, long sCc, long sCh,
             int K, int nc, int nh,
             const float* __restrict__ bias, int bias_n,
             const float* __restrict__ kscale, long sKb, long sKc, long sKh,
             const float* __restrict__ nscale, long sNb, long sNc, long sNh,
             const float* __restrict__ mscale, long sMb, long sMc, long sMh,
             int accum, int outbf)
{
    __shared__ unsigned short As[128 * 64];
    __shared__ unsigned short Ws[128 * 64];

    const int tid = threadIdx.x;
    const int z = blockIdx.z;
    const int h = z % nh;
    const int zc = z / nh;
    const int c = zc % nc;
    const int b = zc / nc;

    const unsigned short* Ab = A + (size_t)(b * sAb + c * sAc + h * sAh);
    const unsigned short* Wb = Wg + (size_t)(b * sWb + c * sWc + h * sWh);
    const size_t coff = (size_t)(b * sCb + c * sCc + h * sCh);
    const float* ksb = kscale ? (kscale + (size_t)(b * sKb + c * sKc + h * sKh)) : nullptr;
    const float* nsb = nscale ? (nscale + (size_t)(b * sNb + c * sNc + h * sNh)) : nullptr;
    const float* msb = mscale ? (mscale + (size_t)(b * sMb + c * sMc + h * sMh)) : nullptr;

    const long bm = (long)blockIdx.y * 128;
    const long bn = (long)blockIdx.x * 128;

    const int lane = tid & 63;
    const int wave = tid >> 6;
    const int wrow = (wave >> 1) * 64;
    const int wcol = (wave & 1) * 64;
    const int lr = lane & 15;
    const int quad = lane >> 4;

    f32x4 acc[4][4] = {};

    for (int k0 = 0; k0 < K; k0 += 64) {
        __syncthreads();
        if (!ksb) {
            #pragma unroll
            for (int q = 0; q < 4; ++q) {
                int cidx = tid + q * 256;      // LDS slot index (16B granules)
                int row = cidx >> 3;
                int sl = cidx & 7;
                int cg = sl ^ (row & 7);       // which global k-chunk this slot holds
                gload_lds16(Ab + (bm + row) * lda + k0 + cg * 8, &As[cidx * 8]);
                gload_lds16(Wb + (bn + row) * ldw + k0 + cg * 8, &Ws[cidx * 8]);
            }
        } else {
            #pragma unroll
            for (int q = 0; q < 4; ++q) {
                int cidx = tid + q * 256;
                int row = cidx >> 3;
                int sl = cidx & 7;
                int cg = sl ^ (row & 7);
                int kk = k0 + cg * 8;
                uint4 va = *(const uint4*)(Ab + (bm + row) * lda + kk);
                const float* ks = ksb + kk;
                unsigned int vv[4] = {va.x, va.y, va.z, va.w};
                #pragma unroll
                for (int e = 0; e < 4; ++e) {
                    float lo = __uint_as_float((vv[e] & 0xFFFFu) << 16) * ks[2 * e];
                    float hi = __uint_as_float(vv[e] & 0xFFFF0000u) * ks[2 * e + 1];
                    vv[e] = (unsigned int)f32_to_bf16(lo) | ((unsigned int)f32_to_bf16(hi) << 16);
                }
                *(uint4*)&As[cidx * 8] = make_uint4(vv[0], vv[1], vv[2], vv[3]);
                uint4 vw = *(const uint4*)(Wb + (bn + row) * ldw + kk);
                *(uint4*)&Ws[cidx * 8] = vw;
            }
        }
        __syncthreads();
        #pragma unroll
        for (int kk = 0; kk < 64; kk += 32) {
            const int cb = (kk >> 3) + quad;   // k-chunk this quad consumes
            bf16x8 av[4], bv[4];
            #pragma unroll
            for (int i = 0; i < 4; ++i) {
                int row = wrow + i * 16 + lr;
                av[i] = *(const bf16x8*)&As[row * 64 + ((cb ^ (row & 7)) * 8)];
            }
            #pragma unroll
            for (int j = 0; j < 4; ++j) {
                int row = wcol + j * 16 + lr;
                bv[j] = *(const bf16x8*)&Ws[row * 64 + ((cb ^ (row & 7)) * 8)];
            }
            #pragma unroll
            for (int i = 0; i < 4; ++i)
                #pragma unroll
                for (int j = 0; j < 4; ++j)
                    acc[i][j] = __builtin_amdgcn_mfma_f32_16x16x32_bf16(av[i], bv[j], acc[i][j], 0, 0, 0);
        }
    }

    #pragma unroll
    for (int i = 0; i < 4; ++i) {
        #pragma unroll
        for (int j = 0; j < 4; ++j) {
            #pragma unroll
            for (int r = 0; r < 4; ++r) {
                long row = bm + wrow + i * 16 + quad * 4 + r;
                long col = bn + wcol + j * 16 + lr;
                float v = acc[i][j][r];
                if (msb) v *= msb[row];
                if (nsb) v *= nsb[col];
                if (bias && col < bias_n) v += bias[col];
                if (outbf) {
                    unsigned short* dst = (unsigned short*)Cmv + coff + row * ldc + col;
                    if (accum) v += bf16_to_f32(*dst);
                    *dst = f32_to_bf16(v);
                } else {
                    float* dst = (float*)Cmv + coff + row * ldc + col;
                    if (accum) *dst += v; else *dst = v;
                }
            }
        }
    }
}

// ---------------------------------------------------------------------------
__global__ __launch_bounds__(256)
void k_convert(const float* __restrict__ src, unsigned short* __restrict__ dst,
               long ncopy, long ntotal)
{
    long i = (long)blockIdx.x * 256 + threadIdx.x;
    long stride = (long)gridDim.x * 256;
    for (; i < ntotal; i += stride)
        dst[i] = (i < ncopy) ? f32_to_bf16(src[i]) : (unsigned short)0;
}

// dt = softplus(dt_raw + dt_bias) per (token, head); Zx is bf16 [NTOK][NXB]
__global__ __launch_bounds__(256)
void k_dt(const unsigned short* __restrict__ Zx, const float* __restrict__ dt_bias,
          float* __restrict__ dtv)
{
    int i = blockIdx.x * 256 + threadIdx.x;
    if (i >= NTOK * N_HEADS) return;
    int t = i >> 5, h = i & 31;
    float raw = bf16_to_f32(Zx[(size_t)t * NXB + CONV_DIM + h]) + dt_bias[h];
    dtv[i] = raw > 20.f ? raw : log1pf(expf(raw));
}

// per (b,c,h): inclusive cumsum of A*dt over l; decay tables
__global__ __launch_bounds__(256)
void k_cumsum(const float* __restrict__ dtv, const float* __restrict__ A_log,
              float* __restrict__ Acs, float* __restrict__ cdec,
              float* __restrict__ eacs, float* __restrict__ ctot)
{
    int z = blockIdx.x;                 // (b*8+c)*32 + h
    int h = z & 31, c = (z >> 5) & 7, b = z >> 8;
    int l = threadIdx.x;
    int t = ((b * 8 + c) << 8) + l;
    float dv = dtv[t * 32 + h];
    float a = -expf(A_log[h]) * dv;
    __shared__ float sb[256];
    sb[l] = a;
    __syncthreads();
    float v = a;
    for (int o = 1; o < 256; o <<= 1) {
        float add = (l >= o) ? sb[l - o] : 0.f;
        __syncthreads();
        v += add;
        sb[l] = v;
        __syncthreads();
    }
    float total = sb[255];
    Acs[(size_t)z * 256 + l] = v;
    cdec[(size_t)z * 256 + l] = expf(total - v) * dv;   // decay_states * dt
    eacs[(size_t)z * 256 + l] = expf(v);                // state_decay_out
    if (l == 255) ctot[(b * 32 + h) * 8 + c] = total;
}

// Tiled causal depthwise conv + silu. 64ch x 64s tiles, LDS transpose.
// Writes: Xt[p][s], Bt[n][s] (s-contig); Y[t][d]=D*x, Bbf/Cbf[t][n] (d-contig).
__global__ __launch_bounds__(256)
void k_conv(const unsigned short* __restrict__ Zx, const float* __restrict__ conv_w,
            const float* __restrict__ conv_b, const float* __restrict__ Dv,
            unsigned short* __restrict__ Xt, unsigned short* __restrict__ Y,
            unsigned short* __restrict__ Bbf, unsigned short* __restrict__ Cbf,
            unsigned short* __restrict__ Bt)
{
    __shared__ unsigned short In[68 * 64];      // [j=0..67][c]; In[j] = s0+j-3
    __shared__ unsigned short OutL[64 * 65];    // [c][s], padded

    const int c0 = blockIdx.x * 64;
    const int s0 = blockIdx.y * 64;
    const int b  = blockIdx.z;
    const int tid = threadIdx.x;

    for (int i = tid; i < 68 * 64; i += 256) {
        int j = i >> 6, c = i & 63;
        int sg = s0 + j - 3;
        unsigned short v = 0;
        if (sg >= 0 && j < 67) v = Zx[(size_t)((b << 11) + sg) * NXB + c0 + c];
        In[i] = v;
    }
    __syncthreads();

    const int cl = tid & 63;
    const int ch = c0 + cl;
    const float w0 = conv_w[ch * 4 + 0], w1 = conv_w[ch * 4 + 1];
    const float w2 = conv_w[ch * 4 + 2], w3 = conv_w[ch * 4 + 3];
    const float cb = conv_b[ch];
    #pragma unroll
    for (int it = 0; it < 16; ++it) {
        int sl = (tid >> 6) + it * 4;
        float a = cb
            + bf16_to_f32(In[(sl + 0) * 64 + cl]) * w0
            + bf16_to_f32(In[(sl + 1) * 64 + cl]) * w1
            + bf16_to_f32(In[(sl + 2) * 64 + cl]) * w2
            + bf16_to_f32(In[(sl + 3) * 64 + cl]) * w3;
        OutL[cl * 65 + sl] = f32_to_bf16(siluf(a));
    }
    __syncthreads();

    // s-contiguous writes (Xt / Bt)
    if (c0 < D_INNER + D_STATE) {
        for (int i = tid; i < 4096; i += 256) {
            int cr = i >> 6, sc = i & 63;
            unsigned short v = OutL[cr * 65 + sc];
            int ch2 = c0 + cr;
            if (ch2 < D_INNER) {
                int hh = ch2 >> 7, p = ch2 & 127;
                Xt[((size_t)(b * 32 + hh) * 128 + p) * 2048 + s0 + sc] = v;
            } else {
                int n = ch2 - D_INNER;
                Bt[((size_t)(b * 128 + n)) * 2048 + s0 + sc] = v;
            }
        }
    }
    // t-major writes (Y = D*x / Bbf / Cbf)
    for (int i = tid; i < 4096; i += 256) {
        int sr = i >> 6, cc = i & 63;
        int t = (b << 11) + s0 + sr;
        int ch2 = c0 + cc;
        unsigned short v = OutL[cc * 65 + sr];
        if (ch2 < D_INNER) {
            Y[(size_t)t * 4096 + ch2] = f32_to_bf16(Dv[ch2 >> 7] * bf16_to_f32(v));
        } else if (ch2 < D_INNER + D_STATE) {
            Bbf[(size_t)t * 128 + (ch2 - D_INNER)] = v;
        } else {
            Cbf[(size_t)t * 128 + (ch2 - D_INNER - D_STATE)] = v;
        }
    }
}

// Wbf[z-z_base][l][s] = (s<=l) * exp(Acs[l]-Acs[s]) * dt[s] * G[bc][l][s]
__global__ __launch_bounds__(256)
void k_wbuild(const float* __restrict__ Acs, const float* __restrict__ dtv,
              const float* __restrict__ G, unsigned short* __restrict__ Wbf,
              int z_base)
{
    int l = blockIdx.x;
    int zr = blockIdx.y;
    int z = z_base + zr;
    int s = threadIdx.x;
    int h = z & 31, c = (z >> 5) & 7, b = z >> 8;
    float w = 0.f;
    if (s <= l) {
        float e = expf(Acs[(size_t)z * 256 + l] - Acs[(size_t)z * 256 + s]);
        int t = ((b * 8 + c) << 8) + s;
        w = e * dtv[t * 32 + h] * G[(size_t)(b * 8 + c) * 65536 + l * 256 + s];
    }
    Wbf[(size_t)zr * 65536 + l * 256 + s] = f32_to_bf16(w);
}

// sequential 8-chunk state recurrence; writes incoming state (bf16) per chunk
__global__ __launch_bounds__(256)
void k_recur(const float* __restrict__ Sloc, const float* __restrict__ ctot,
             unsigned short* __restrict__ Sin)
{
    int i = blockIdx.x * 256 + threadIdx.x;    // over 2*32*128*128
    int n = i & 127, p = (i >> 7) & 127, h = (i >> 14) & 31, b = i >> 19;
    float s = 0.f;
    for (int c = 0; c < 8; ++c) {
        size_t idx = ((((size_t)(b * 8 + c) * 32 + h) * 128 + p) * 128 + n);
        Sin[idx] = f32_to_bf16(s);
        s = s * expf(ctot[(b * 32 + h) * 8 + c]) + Sloc[idx];
    }
}

// y = Y[t][d] (already Y_diag+Y_off+D*x) ; *= silu(z) ; RMSNorm*norm_w -> bf16
__global__ __launch_bounds__(256)
void k_combine(const unsigned short* __restrict__ Y, const unsigned short* __restrict__ Zz,
               const float* __restrict__ norm_w, unsigned short* __restrict__ Ybf)
{
    int t = blockIdx.x;
    int tid = threadIdx.x;
    const unsigned int* Yr = (const unsigned int*)(Y + (size_t)t * 4096);
    const unsigned int* Zr = (const unsigned int*)(Zz + (size_t)t * 4096);
    float vals[16];
    float ss = 0.f;
    #pragma unroll
    for (int it = 0; it < 8; ++it) {
        int j = tid + it * 256;
        unsigned int y2 = Yr[j], z2 = Zr[j];
        float y0 = __uint_as_float((y2 & 0xFFFFu) << 16);
        float y1 = __uint_as_float(y2 & 0xFFFF0000u);
        float z0 = __uint_as_float((z2 & 0xFFFFu) << 16);
        float z1 = __uint_as_float(z2 & 0xFFFF0000u);
        y0 *= siluf(z0);
        y1 *= siluf(z1);
        vals[2 * it] = y0;
        vals[2 * it + 1] = y1;
        ss += y0 * y0 + y1 * y1;
    }
    #pragma unroll
    for (int o = 32; o > 0; o >>= 1) ss += __shfl_down(ss, o, 64);
    __shared__ float red[4];
    if ((tid & 63) == 0) red[tid >> 6] = ss;
    __syncthreads();
    float tot = red[0] + red[1] + red[2] + red[3];
    float scale = rsqrtf(tot / 4096.f + 1e-5f);
    unsigned int* Yw = (unsigned int*)(Ybf + (size_t)t * 4096);
    #pragma unroll
    for (int it = 0; it < 8; ++it) {
        int j = tid + it * 256;
        unsigned short o0 = f32_to_bf16(vals[2 * it] * scale * norm_w[2 * j]);
        unsigned short o1 = f32_to_bf16(vals[2 * it + 1] * scale * norm_w[2 * j + 1]);
        Yw[j] = (unsigned int)o0 | ((unsigned int)o1 << 16);
    }
}

// ---------------------------------------------------------------------------
extern "C" void kernel_launch(void* const* d_in, const int* in_sizes, int n_in,
                              void* d_out, int out_size, void* d_ws, size_t ws_size,
                              hipStream_t stream)
{
    if (n_in < 11) return;
    const float* inputs     = (const float*)d_in[0];
    const float* in_proj_w  = (const float*)d_in[1];
    const float* in_proj_b  = (const float*)d_in[2];
    const float* out_proj_w = (const float*)d_in[3];
    const float* out_proj_b = (const float*)d_in[4];
    const float* conv_w     = (const float*)d_in[5];
    const float* conv_b     = (const float*)d_in[6];
    const float* dt_bias    = (const float*)d_in[7];
    const float* A_log      = (const float*)d_in[8];
    const float* Dv         = (const float*)d_in[9];
    const float* norm_w     = (const float*)d_in[10];
    float* out = (float*)d_out;

    // ---- workspace plan (aliased regions) ----
    char* base = (char*)d_ws;
    const size_t SZ_ABF  = (size_t)NTOK * DIMM * 2;            // 16.78 MB
    const size_t SZ_W1   = (size_t)8576 * DIMM * 2;            // 35.13 MB
    const size_t SZ_R0   = SZ_ABF + SZ_W1;                     // 51.90 MB
    const size_t SZ_ZZ   = (size_t)NTOK * 4096 * 2;            // 33.55 MB
    const size_t SZ_R3   = (size_t)NTOK * NXB * 2;             // 36.70 MB
    const size_t SZ_XT   = (size_t)BATCH * 32 * 128 * 2048 * 2;// 33.55 MB
    const size_t SZ_R2   = (size_t)256 * 65536 * 2;            // 33.55 MB
    size_t off = 0;
    char* R0   = base + off; off += SZ_R0;
    char* Zz   = base + off; off += SZ_ZZ;
    char* R3   = base + off; off += SZ_R3;
    char* XtB  = base + off; off += SZ_XT;
    char* R2   = base + off; off += SZ_R2;
    unsigned short* Bbf = (unsigned short*)(base + off); off += (size_t)NTOK * 128 * 2;
    unsigned short* Cbf = (unsigned short*)(base + off); off += (size_t)NTOK * 128 * 2;
    unsigned short* Bt  = (unsigned short*)(base + off); off += (size_t)BATCH * 128 * 2048 * 2;
    float* dtv  = (float*)(base + off); off += (size_t)NTOK * 32 * 4;
    float* Acs  = (float*)(base + off); off += (size_t)512 * 256 * 4;
    float* cdec = (float*)(base + off); off += (size_t)512 * 256 * 4;
    float* eacs = (float*)(base + off); off += (size_t)512 * 256 * 4;
    float* ctot = (float*)(base + off); off += (size_t)512 * 4;
    float* G    = (float*)(base + off); off += (size_t)16 * 65536 * 4;
    if (off > ws_size) return;   // ws too small (signature: absmax == max|ref|)

    unsigned short* Abf  = (unsigned short*)R0;                 // dead after GEMM1
    unsigned short* W1bf = (unsigned short*)(R0 + SZ_ABF);      // dead after GEMM1
    unsigned short* Sin  = (unsigned short*)R0;                 // steps 9-10 (16.78 MB)
    unsigned short* Y    = (unsigned short*)(R0 + SZ_ABF);      // steps 4-12 (33.55 MB)
    unsigned short* Zzb  = (unsigned short*)Zz;                 // live till combine
    unsigned short* Zxb  = (unsigned short*)R3;                 // dead after conv
    unsigned short* Ybf  = (unsigned short*)R3;                 // steps 12-13
    unsigned short* Xt   = (unsigned short*)XtB;
    unsigned short* Wbf  = (unsigned short*)R2;                 // staged, 256 z at a time
    unsigned short* W2bf = (unsigned short*)R2;                 // after Y_diag stages
    float* Sloc = (float*)d_out;                                // steps 8-9, 33.55 MB

    // 1. converts
    k_convert<<<2048, 256, 0, stream>>>(inputs, Abf, (long)NTOK * DIMM, (long)NTOK * DIMM);
    k_convert<<<2048, 256, 0, stream>>>(in_proj_w, W1bf, (long)D_IN_PROJ * DIMM, (long)8576 * DIMM);

    // 2a. GEMM1 z-part: Zzb[4096][4096] (bf16)
    gemm_bt<<<dim3(32, 32, 1), 256, 0, stream>>>(
        Abf, DIMM, 0, 0, 0,  W1bf, DIMM, 0, 0, 0,
        Zzb, 4096, 0, 0, 0,  DIMM, 1, 1,
        in_proj_b, 4096,  nullptr, 0, 0, 0,  nullptr, 0, 0, 0,  nullptr, 0, 0, 0,  0, 1);
    // 2b. GEMM1 xBC+dt part: Zxb[4096][4480] (bf16)
    gemm_bt<<<dim3(35, 32, 1), 256, 0, stream>>>(
        Abf, DIMM, 0, 0, 0,  W1bf + (size_t)4096 * DIMM, DIMM, 0, 0, 0,
        Zxb, NXB, 0, 0, 0,  DIMM, 1, 1,
        in_proj_b + 4096, D_IN_PROJ - 4096,  nullptr, 0, 0, 0,  nullptr, 0, 0, 0,
        nullptr, 0, 0, 0,  0, 1);

    // 3. dt + cumsum tables
    k_dt<<<(NTOK * N_HEADS) / 256, 256, 0, stream>>>(Zxb, dt_bias, dtv);
    k_cumsum<<<512, 256, 0, stream>>>(dtv, A_log, Acs, cdec, eacs, ctot);

    // 4. conv + silu + splits; initializes Y[t][d] = D*x
    k_conv<<<dim3(68, 32, 2), 256, 0, stream>>>(Zxb, conv_w, conv_b, Dv, Xt, Y, Bbf, Cbf, Bt);

    // 5. G = C @ B^T per (b,c):  M=256(l) N=256(s) K=128  (f32 out)
    gemm_bt<<<dim3(2, 2, 16), 256, 0, stream>>>(
        Cbf, 128, 2048L * 128, 256L * 128, 0,
        Bbf, 128, 2048L * 128, 256L * 128, 0,
        G, 256, 8L * 65536, 65536, 0,
        128, 8, 1,
        nullptr, 0, nullptr, 0, 0, 0, nullptr, 0, 0, 0, nullptr, 0, 0, 0, 0, 0);

    // 6/7. two stages (= batch b): build Wbf then Y[t][d] += Wbf @ Xt^T
    for (int s = 0; s < 2; ++s) {
        k_wbuild<<<dim3(256, 256, 1), 256, 0, stream>>>(Acs, dtv, G, Wbf, s * 256);
        gemm_bt<<<dim3(1, 2, 256), 256, 0, stream>>>(
            Wbf, 256, 0, 32L * 65536, 65536,
            Xt + (size_t)s * 32 * 128 * 2048, 2048, 0, 256, 128L * 2048,
            Y + (size_t)s * 2048 * 4096, 4096, 0, 256L * 4096, 128,
            256, 8, 32,
            nullptr, 0,
            nullptr, 0, 0, 0,  nullptr, 0, 0, 0,  nullptr, 0, 0, 0,
            1, 1);
    }

    // 8. local states[p][n] = (Xt * cdec) @ Bt^T  (f32 out into d_out scratch)
    gemm_bt<<<dim3(1, 1, 512), 256, 0, stream>>>(
        Xt, 2048, 32L * 128 * 2048, 256, 128L * 2048,
        Bt, 2048, 128L * 2048, 256, 0,
        Sloc, 128, 8L * 32 * 16384, 32L * 16384, 16384,
        256, 8, 32,
        nullptr, 0,
        cdec, 8L * 32 * 256, 32L * 256, 256,
        nullptr, 0, 0, 0,  nullptr, 0, 0, 0,
        0, 0);

    // 9. chunk recurrence -> incoming states (bf16)
    k_recur<<<4096, 256, 0, stream>>>(Sloc, ctot, Sin);

    // 10. Y[t][d] += exp(Acs[l]) * (Cbf @ Sin^T)
    gemm_bt<<<dim3(1, 2, 512), 256, 0, stream>>>(
        Cbf, 128, 2048L * 128, 256L * 128, 0,
        Sin, 128, 8L * 32 * 16384, 32L * 16384, 16384,
        Y, 4096, 2048L * 4096, 256L * 4096, 128,
        128, 8, 32,
        nullptr, 0,
        nullptr, 0, 0, 0,  nullptr, 0, 0, 0,
        eacs, 8L * 32 * 256, 32L * 256, 256,
        1, 1);

    // 11. out_proj weight convert (into dead Wbf region)
    k_convert<<<2048, 256, 0, stream>>>(out_proj_w, W2bf, (long)DIMM * D_INNER, (long)DIMM * D_INNER);

    // 12. combine: *silu(z), RMSNorm -> Ybf (into dead Zxb region)
    k_combine<<<NTOK, 256, 0, stream>>>(Y, Zzb, norm_w, Ybf);

    // 13. GEMM2: out[4096][2048] = Ybf @ W2bf^T + out_proj_b  (f32 out)
    gemm_bt<<<dim3(16, 32, 1), 256, 0, stream>>>(
        Ybf, D_INNER, 0, 0, 0,
        W2bf, D_INNER, 0, 0, 0,
        out, DIMM, 0, 0, 0,
        D_INNER, 1, 1,
        out_proj_b, DIMM,
        nullptr, 0, 0, 0,  nullptr, 0, 0, 0,  nullptr, 0, 0, 0,
        0, 0);
}

// Round 5
// 765.332 us; speedup vs baseline: 1.5768x; 1.0129x over previous
//
#include <hip/hip_runtime.h>
#include <math.h>

#define DIMM 2048
#define D_INNER 4096
#define D_STATE 128
#define N_HEADS 32
#define CHUNK 256
#define CONV_DIM 4352
#define D_IN_PROJ 8480
#define BATCH 2
#define SEQ 2048
#define NTOK 4096
#define NCHUNK 8
#define HEADDIM 128
#define NXB 4480            // padded width of the xBC+dt GEMM1 output (35*128)

typedef short bf16x8 __attribute__((ext_vector_type(8)));
typedef float f32x4 __attribute__((ext_vector_type(4)));

__device__ __forceinline__ unsigned short f32_to_bf16(float f) {
    unsigned int u = __float_as_uint(f);
    unsigned int r = (u + 0x7FFFu + ((u >> 16) & 1u)) >> 16;
    return (unsigned short)r;
}
__device__ __forceinline__ float bf16_to_f32(unsigned short h) {
    return __uint_as_float(((unsigned int)h) << 16);
}
__device__ __forceinline__ float siluf(float v) { return v / (1.f + expf(-v)); }

// async global->LDS DMA, 16 bytes per lane. LDS dest must be uniform+lane*16.
__device__ __forceinline__ void gload_lds16(const unsigned short* g, unsigned short* l) {
    __builtin_amdgcn_global_load_lds(
        (const __attribute__((address_space(1))) unsigned int*)((const void*)g),
        (__attribute__((address_space(3))) unsigned int*)((void*)l),
        16, 0, 0);
}

// ---------------------------------------------------------------------------
// Generic batched bf16 GEMM:  C[m][n] = sum_k A[m][k] * W[n][k]  (+bias/scales)
// Both operands row-major, K contiguous. Tile 128x128, BK=64, 4 waves 2x2.
// Tile order: bands of 8 M-tiles, M-fastest -> with bid%8 XCD round-robin each
// XCD keeps one A-row band resident in its L2 while sweeping N (fetch ~= A once
// + W once per XCD instead of ~7x over-fetch).
// LDS tiles XOR-swizzled: slot (row, s) holds global k-chunk (s ^ (row&7)).
// Staging via global_load_lds (width 16); kscale path falls back to VALU.
// kscale: A[m][k] *= kscale[k].  nscale: col scale.  mscale: row scale.
// ---------------------------------------------------------------------------
__global__ __launch_bounds__(256)
void gemm_bt(const unsigned short* __restrict__ A, long lda, long sAb, long sAc, long sAh,
             const unsigned short* __restrict__ Wg, long ldw, long sWb, long sWc, long sWh,
             void* __restrict__ Cmv, long ldc, long sCb, long sCc, long sCh,
             int K, int nc, int nh,
             const float* __restrict__ bias, int bias_n,
             const float* __restrict__ kscale, long sKb, long sKc, long sKh,
             const float* __restrict__ nscale, long sNb, long sNc, long sNh,
             const float* __restrict__ mscale, long sMb, long sMc, long sMh,
             int accum, int outbf)
{
    __shared__ unsigned short As[128 * 64];
    __shared__ unsigned short Ws[128 * 64];

    const int tid = threadIdx.x;
    const int z = blockIdx.z;
    const int h = z % nh;
    const int zc = z / nh;
    const int c = zc % nc;
    const int b = zc / nc;

    // --- XCD-aware supertile swizzle (band of 8 M-tiles, M-fastest) ---
    const int tilesN = gridDim.x, tilesM = gridDim.y;
    int bid = (int)blockIdx.y * tilesN + (int)blockIdx.x;
    const int band = (tilesM < 8) ? tilesM : 8;
    const int per = band * tilesN;
    int g = bid / per;
    int r = bid % per;
    int rows = tilesM - g * band; if (rows > band) rows = band;
    int mt = g * band + (r % rows);
    int nt = r / rows;

    const unsigned short* Ab = A + (size_t)(b * sAb + c * sAc + h * sAh);
    const unsigned short* Wb = Wg + (size_t)(b * sWb + c * sWc + h * sWh);
    const size_t coff = (size_t)(b * sCb + c * sCc + h * sCh);
    const float* ksb = kscale ? (kscale + (size_t)(b * sKb + c * sKc + h * sKh)) : nullptr;
    const float* nsb = nscale ? (nscale + (size_t)(b * sNb + c * sNc + h * sNh)) : nullptr;
    const float* msb = mscale ? (mscale + (size_t)(b * sMb + c * sMc + h * sMh)) : nullptr;

    const long bm = (long)mt * 128;
    const long bn = (long)nt * 128;

    const int lane = tid & 63;
    const int wave = tid >> 6;
    const int wrow = (wave >> 1) * 64;
    const int wcol = (wave & 1) * 64;
    const int lr = lane & 15;
    const int quad = lane >> 4;

    f32x4 acc[4][4] = {};

    for (int k0 = 0; k0 < K; k0 += 64) {
        __syncthreads();
        if (!ksb) {
            #pragma unroll
            for (int q = 0; q < 4; ++q) {
                int cidx = tid + q * 256;      // LDS slot index (16B granules)
                int row = cidx >> 3;
                int sl = cidx & 7;
                int cg = sl ^ (row & 7);       // which global k-chunk this slot holds
                gload_lds16(Ab + (bm + row) * lda + k0 + cg * 8, &As[cidx * 8]);
                gload_lds16(Wb + (bn + row) * ldw + k0 + cg * 8, &Ws[cidx * 8]);
            }
        } else {
            #pragma unroll
            for (int q = 0; q < 4; ++q) {
                int cidx = tid + q * 256;
                int row = cidx >> 3;
                int sl = cidx & 7;
                int cg = sl ^ (row & 7);
                int kk = k0 + cg * 8;
                uint4 va = *(const uint4*)(Ab + (bm + row) * lda + kk);
                const float* ks = ksb + kk;
                unsigned int vv[4] = {va.x, va.y, va.z, va.w};
                #pragma unroll
                for (int e = 0; e < 4; ++e) {
                    float lo = __uint_as_float((vv[e] & 0xFFFFu) << 16) * ks[2 * e];
                    float hi = __uint_as_float(vv[e] & 0xFFFF0000u) * ks[2 * e + 1];
                    vv[e] = (unsigned int)f32_to_bf16(lo) | ((unsigned int)f32_to_bf16(hi) << 16);
                }
                *(uint4*)&As[cidx * 8] = make_uint4(vv[0], vv[1], vv[2], vv[3]);
                uint4 vw = *(const uint4*)(Wb + (bn + row) * ldw + kk);
                *(uint4*)&Ws[cidx * 8] = vw;
            }
        }
        __syncthreads();
        #pragma unroll
        for (int kk = 0; kk < 64; kk += 32) {
            const int cb = (kk >> 3) + quad;   // k-chunk this quad consumes
            bf16x8 av[4], bv[4];
            #pragma unroll
            for (int i = 0; i < 4; ++i) {
                int row = wrow + i * 16 + lr;
                av[i] = *(const bf16x8*)&As[row * 64 + ((cb ^ (row & 7)) * 8)];
            }
            #pragma unroll
            for (int j = 0; j < 4; ++j) {
                int row = wcol + j * 16 + lr;
                bv[j] = *(const bf16x8*)&Ws[row * 64 + ((cb ^ (row & 7)) * 8)];
            }
            #pragma unroll
            for (int i = 0; i < 4; ++i)
                #pragma unroll
                for (int j = 0; j < 4; ++j)
                    acc[i][j] = __builtin_amdgcn_mfma_f32_16x16x32_bf16(av[i], bv[j], acc[i][j], 0, 0, 0);
        }
    }

    #pragma unroll
    for (int i = 0; i < 4; ++i) {
        #pragma unroll
        for (int j = 0; j < 4; ++j) {
            #pragma unroll
            for (int r2 = 0; r2 < 4; ++r2) {
                long row = bm + wrow + i * 16 + quad * 4 + r2;
                long col = bn + wcol + j * 16 + lr;
                float v = acc[i][j][r2];
                if (msb) v *= msb[row];
                if (nsb) v *= nsb[col];
                if (bias && col < bias_n) v += bias[col];
                if (outbf) {
                    unsigned short* dst = (unsigned short*)Cmv + coff + row * ldc + col;
                    if (accum) v += bf16_to_f32(*dst);
                    *dst = f32_to_bf16(v);
                } else {
                    float* dst = (float*)Cmv + coff + row * ldc + col;
                    if (accum) *dst += v; else *dst = v;
                }
            }
        }
    }
}

// ---------------------------------------------------------------------------
// vectorized f32 -> bf16 convert (4 elems/thread); sizes multiple of 4
__global__ __launch_bounds__(256)
void k_convert(const float* __restrict__ src, unsigned short* __restrict__ dst,
               long ncopy, long ntotal)
{
    long i4 = ((long)blockIdx.x * 256 + threadIdx.x) * 4;
    long stride = (long)gridDim.x * 256 * 4;
    for (; i4 < ntotal; i4 += stride) {
        ushort4 o;
        if (i4 + 3 < ncopy) {
            float4 v = *(const float4*)(src + i4);
            o.x = f32_to_bf16(v.x); o.y = f32_to_bf16(v.y);
            o.z = f32_to_bf16(v.z); o.w = f32_to_bf16(v.w);
        } else {
            o.x = (i4 + 0 < ncopy) ? f32_to_bf16(src[i4 + 0]) : 0;
            o.y = (i4 + 1 < ncopy) ? f32_to_bf16(src[i4 + 1]) : 0;
            o.z = (i4 + 2 < ncopy) ? f32_to_bf16(src[i4 + 2]) : 0;
            o.w = (i4 + 3 < ncopy) ? f32_to_bf16(src[i4 + 3]) : 0;
        }
        *(ushort4*)(dst + i4) = o;
    }
}

// per (b,c,h): softplus(dt)+cumsum of A*dt over l; decay tables (k_dt fused)
__global__ __launch_bounds__(256)
void k_cumsum(const unsigned short* __restrict__ Zx, const float* __restrict__ dt_bias,
              const float* __restrict__ A_log,
              float* __restrict__ dtv, float* __restrict__ Acs,
              float* __restrict__ cdec, float* __restrict__ eacs,
              float* __restrict__ ctot)
{
    int z = blockIdx.x;                 // (b*8+c)*32 + h
    int h = z & 31, c = (z >> 5) & 7, b = z >> 8;
    int l = threadIdx.x;
    int t = ((b * 8 + c) << 8) + l;
    float raw = bf16_to_f32(Zx[(size_t)t * NXB + CONV_DIM + h]) + dt_bias[h];
    float dv = raw > 20.f ? raw : log1pf(expf(raw));
    dtv[t * 32 + h] = dv;
    float a = -expf(A_log[h]) * dv;
    __shared__ float sb[256];
    sb[l] = a;
    __syncthreads();
    float v = a;
    for (int o = 1; o < 256; o <<= 1) {
        float add = (l >= o) ? sb[l - o] : 0.f;
        __syncthreads();
        v += add;
        sb[l] = v;
        __syncthreads();
    }
    float total = sb[255];
    Acs[(size_t)z * 256 + l] = v;
    cdec[(size_t)z * 256 + l] = expf(total - v) * dv;   // decay_states * dt
    eacs[(size_t)z * 256 + l] = expf(v);                // state_decay_out
    if (l == 255) ctot[(b * 32 + h) * 8 + c] = total;
}

// Tiled causal depthwise conv + silu. 64ch x 64s tiles, LDS transpose.
// Writes: Xt[p][s], Bt[n][s] (s-contig); Y[t][d]=D*x, Bbf/Cbf[t][n] (d-contig).
__global__ __launch_bounds__(256)
void k_conv(const unsigned short* __restrict__ Zx, const float* __restrict__ conv_w,
            const float* __restrict__ conv_b, const float* __restrict__ Dv,
            unsigned short* __restrict__ Xt, unsigned short* __restrict__ Y,
            unsigned short* __restrict__ Bbf, unsigned short* __restrict__ Cbf,
            unsigned short* __restrict__ Bt)
{
    __shared__ unsigned short In[68 * 64];      // [j=0..67][c]; In[j] = s0+j-3
    __shared__ unsigned short OutL[64 * 65];    // [c][s], padded

    const int c0 = blockIdx.x * 64;
    const int s0 = blockIdx.y * 64;
    const int b  = blockIdx.z;
    const int tid = threadIdx.x;

    for (int i = tid; i < 68 * 64; i += 256) {
        int j = i >> 6, c = i & 63;
        int sg = s0 + j - 3;
        unsigned short v = 0;
        if (sg >= 0 && j < 67) v = Zx[(size_t)((b << 11) + sg) * NXB + c0 + c];
        In[i] = v;
    }
    __syncthreads();

    const int cl = tid & 63;
    const int ch = c0 + cl;
    const float w0 = conv_w[ch * 4 + 0], w1 = conv_w[ch * 4 + 1];
    const float w2 = conv_w[ch * 4 + 2], w3 = conv_w[ch * 4 + 3];
    const float cb = conv_b[ch];
    #pragma unroll
    for (int it = 0; it < 16; ++it) {
        int sl = (tid >> 6) + it * 4;
        float a = cb
            + bf16_to_f32(In[(sl + 0) * 64 + cl]) * w0
            + bf16_to_f32(In[(sl + 1) * 64 + cl]) * w1
            + bf16_to_f32(In[(sl + 2) * 64 + cl]) * w2
            + bf16_to_f32(In[(sl + 3) * 64 + cl]) * w3;
        OutL[cl * 65 + sl] = f32_to_bf16(siluf(a));
    }
    __syncthreads();

    // s-contiguous writes (Xt / Bt)
    if (c0 < D_INNER + D_STATE) {
        for (int i = tid; i < 4096; i += 256) {
            int cr = i >> 6, sc = i & 63;
            unsigned short v = OutL[cr * 65 + sc];
            int ch2 = c0 + cr;
            if (ch2 < D_INNER) {
                int hh = ch2 >> 7, p = ch2 & 127;
                Xt[((size_t)(b * 32 + hh) * 128 + p) * 2048 + s0 + sc] = v;
            } else {
                int n = ch2 - D_INNER;
                Bt[((size_t)(b * 128 + n)) * 2048 + s0 + sc] = v;
            }
        }
    }
    // t-major writes (Y = D*x / Bbf / Cbf)
    for (int i = tid; i < 4096; i += 256) {
        int sr = i >> 6, cc = i & 63;
        int t = (b << 11) + s0 + sr;
        int ch2 = c0 + cc;
        unsigned short v = OutL[cc * 65 + sr];
        if (ch2 < D_INNER) {
            Y[(size_t)t * 4096 + ch2] = f32_to_bf16(Dv[ch2 >> 7] * bf16_to_f32(v));
        } else if (ch2 < D_INNER + D_STATE) {
            Bbf[(size_t)t * 128 + (ch2 - D_INNER)] = v;
        } else {
            Cbf[(size_t)t * 128 + (ch2 - D_INNER - D_STATE)] = v;
        }
    }
}

// Wbf[z-z_base][l][s] = (s<=l) * exp(Acs[l]-Acs[s]) * dt[s] * G[bc][l][s]
__global__ __launch_bounds__(256)
void k_wbuild(const float* __restrict__ Acs, const float* __restrict__ dtv,
              const float* __restrict__ G, unsigned short* __restrict__ Wbf,
              int z_base)
{
    int l = blockIdx.x;
    int zr = blockIdx.y;
    int z = z_base + zr;
    int s = threadIdx.x;
    int h = z & 31, c = (z >> 5) & 7, b = z >> 8;
    float w = 0.f;
    if (s <= l) {
        float e = expf(Acs[(size_t)z * 256 + l] - Acs[(size_t)z * 256 + s]);
        int t = ((b * 8 + c) << 8) + s;
        w = e * dtv[t * 32 + h] * G[(size_t)(b * 8 + c) * 65536 + l * 256 + s];
    }
    Wbf[(size_t)zr * 65536 + l * 256 + s] = f32_to_bf16(w);
}

// sequential 8-chunk state recurrence; writes incoming state (bf16) per chunk
__global__ __launch_bounds__(256)
void k_recur(const float* __restrict__ Sloc, const float* __restrict__ ctot,
             unsigned short* __restrict__ Sin)
{
    int i = blockIdx.x * 256 + threadIdx.x;    // over 2*32*128*128
    int n = i & 127, p = (i >> 7) & 127, h = (i >> 14) & 31, b = i >> 19;
    float s = 0.f;
    for (int c = 0; c < 8; ++c) {
        size_t idx = ((((size_t)(b * 8 + c) * 32 + h) * 128 + p) * 128 + n);
        Sin[idx] = f32_to_bf16(s);
        s = s * expf(ctot[(b * 32 + h) * 8 + c]) + Sloc[idx];
    }
}

// y = Y[t][d] (already Y_diag+Y_off+D*x) ; *= silu(z) ; RMSNorm*norm_w -> bf16
__global__ __launch_bounds__(256)
void k_combine(const unsigned short* __restrict__ Y, const unsigned short* __restrict__ Zz,
               const float* __restrict__ norm_w, unsigned short* __restrict__ Ybf)
{
    int t = blockIdx.x;
    int tid = threadIdx.x;
    const unsigned int* Yr = (const unsigned int*)(Y + (size_t)t * 4096);
    const unsigned int* Zr = (const unsigned int*)(Zz + (size_t)t * 4096);
    float vals[16];
    float ss = 0.f;
    #pragma unroll
    for (int it = 0; it < 8; ++it) {
        int j = tid + it * 256;
        unsigned int y2 = Yr[j], z2 = Zr[j];
        float y0 = __uint_as_float((y2 & 0xFFFFu) << 16);
        float y1 = __uint_as_float(y2 & 0xFFFF0000u);
        float z0 = __uint_as_float((z2 & 0xFFFFu) << 16);
        float z1 = __uint_as_float(z2 & 0xFFFF0000u);
        y0 *= siluf(z0);
        y1 *= siluf(z1);
        vals[2 * it] = y0;
        vals[2 * it + 1] = y1;
        ss += y0 * y0 + y1 * y1;
    }
    #pragma unroll
    for (int o = 32; o > 0; o >>= 1) ss += __shfl_down(ss, o, 64);
    __shared__ float red[4];
    if ((tid & 63) == 0) red[tid >> 6] = ss;
    __syncthreads();
    float tot = red[0] + red[1] + red[2] + red[3];
    float scale = rsqrtf(tot / 4096.f + 1e-5f);
    unsigned int* Yw = (unsigned int*)(Ybf + (size_t)t * 4096);
    #pragma unroll
    for (int it = 0; it < 8; ++it) {
        int j = tid + it * 256;
        unsigned short o0 = f32_to_bf16(vals[2 * it] * scale * norm_w[2 * j]);
        unsigned short o1 = f32_to_bf16(vals[2 * it + 1] * scale * norm_w[2 * j + 1]);
        Yw[j] = (unsigned int)o0 | ((unsigned int)o1 << 16);
    }
}

// ---------------------------------------------------------------------------
extern "C" void kernel_launch(void* const* d_in, const int* in_sizes, int n_in,
                              void* d_out, int out_size, void* d_ws, size_t ws_size,
                              hipStream_t stream)
{
    if (n_in < 11) return;
    const float* inputs     = (const float*)d_in[0];
    const float* in_proj_w  = (const float*)d_in[1];
    const float* in_proj_b  = (const float*)d_in[2];
    const float* out_proj_w = (const float*)d_in[3];
    const float* out_proj_b = (const float*)d_in[4];
    const float* conv_w     = (const float*)d_in[5];
    const float* conv_b     = (const float*)d_in[6];
    const float* dt_bias    = (const float*)d_in[7];
    const float* A_log      = (const float*)d_in[8];
    const float* Dv         = (const float*)d_in[9];
    const float* norm_w     = (const float*)d_in[10];
    float* out = (float*)d_out;

    // ---- workspace plan (aliased regions) ----
    char* base = (char*)d_ws;
    const size_t SZ_ABF  = (size_t)NTOK * DIMM * 2;            // 16.78 MB
    const size_t SZ_W1   = (size_t)8576 * DIMM * 2;            // 35.13 MB
    const size_t SZ_R0   = SZ_ABF + SZ_W1;                     // 51.90 MB
    const size_t SZ_ZZ   = (size_t)NTOK * 4096 * 2;            // 33.55 MB
    const size_t SZ_R3   = (size_t)NTOK * NXB * 2;             // 36.70 MB
    const size_t SZ_XT   = (size_t)BATCH * 32 * 128 * 2048 * 2;// 33.55 MB
    const size_t SZ_R2   = (size_t)256 * 65536 * 2;            // 33.55 MB
    size_t off = 0;
    char* R0   = base + off; off += SZ_R0;
    char* Zz   = base + off; off += SZ_ZZ;
    char* R3   = base + off; off += SZ_R3;
    char* XtB  = base + off; off += SZ_XT;
    char* R2   = base + off; off += SZ_R2;
    unsigned short* Bbf = (unsigned short*)(base + off); off += (size_t)NTOK * 128 * 2;
    unsigned short* Cbf = (unsigned short*)(base + off); off += (size_t)NTOK * 128 * 2;
    unsigned short* Bt  = (unsigned short*)(base + off); off += (size_t)BATCH * 128 * 2048 * 2;
    float* dtv  = (float*)(base + off); off += (size_t)NTOK * 32 * 4;
    float* Acs  = (float*)(base + off); off += (size_t)512 * 256 * 4;
    float* cdec = (float*)(base + off); off += (size_t)512 * 256 * 4;
    float* eacs = (float*)(base + off); off += (size_t)512 * 256 * 4;
    float* ctot = (float*)(base + off); off += (size_t)512 * 4;
    float* G    = (float*)(base + off); off += (size_t)16 * 65536 * 4;
    if (off > ws_size) return;   // ws too small (signature: absmax == max|ref|)

    unsigned short* Abf  = (unsigned short*)R0;                 // dead after GEMM1
    unsigned short* W1bf = (unsigned short*)(R0 + SZ_ABF);      // dead after GEMM1
    unsigned short* Sin  = (unsigned short*)R0;                 // steps 9-10 (16.78 MB)
    unsigned short* Y    = (unsigned short*)(R0 + SZ_ABF);      // steps 4-12 (33.55 MB)
    unsigned short* Zzb  = (unsigned short*)Zz;                 // live till combine
    unsigned short* Zxb  = (unsigned short*)R3;                 // dead after conv
    unsigned short* Ybf  = (unsigned short*)R3;                 // steps 12-13
    unsigned short* Xt   = (unsigned short*)XtB;
    unsigned short* Wbf  = (unsigned short*)R2;                 // staged, 256 z at a time
    unsigned short* W2bf = (unsigned short*)R2;                 // after Y_diag stages
    float* Sloc = (float*)d_out;                                // steps 8-9, 33.55 MB

    // 1. converts
    k_convert<<<2048, 256, 0, stream>>>(inputs, Abf, (long)NTOK * DIMM, (long)NTOK * DIMM);
    k_convert<<<2048, 256, 0, stream>>>(in_proj_w, W1bf, (long)D_IN_PROJ * DIMM, (long)8576 * DIMM);

    // 2a. GEMM1 z-part: Zzb[4096][4096] (bf16)
    gemm_bt<<<dim3(32, 32, 1), 256, 0, stream>>>(
        Abf, DIMM, 0, 0, 0,  W1bf, DIMM, 0, 0, 0,
        Zzb, 4096, 0, 0, 0,  DIMM, 1, 1,
        in_proj_b, 4096,  nullptr, 0, 0, 0,  nullptr, 0, 0, 0,  nullptr, 0, 0, 0,  0, 1);
    // 2b. GEMM1 xBC+dt part: Zxb[4096][4480] (bf16)
    gemm_bt<<<dim3(35, 32, 1), 256, 0, stream>>>(
        Abf, DIMM, 0, 0, 0,  W1bf + (size_t)4096 * DIMM, DIMM, 0, 0, 0,
        Zxb, NXB, 0, 0, 0,  DIMM, 1, 1,
        in_proj_b + 4096, D_IN_PROJ - 4096,  nullptr, 0, 0, 0,  nullptr, 0, 0, 0,
        nullptr, 0, 0, 0,  0, 1);

    // 3. softplus(dt) + cumsum tables (fused)
    k_cumsum<<<512, 256, 0, stream>>>(Zxb, dt_bias, A_log, dtv, Acs, cdec, eacs, ctot);

    // 4. conv + silu + splits; initializes Y[t][d] = D*x
    k_conv<<<dim3(68, 32, 2), 256, 0, stream>>>(Zxb, conv_w, conv_b, Dv, Xt, Y, Bbf, Cbf, Bt);

    // 5. G = C @ B^T per (b,c):  M=256(l) N=256(s) K=128  (f32 out)
    gemm_bt<<<dim3(2, 2, 16), 256, 0, stream>>>(
        Cbf, 128, 2048L * 128, 256L * 128, 0,
        Bbf, 128, 2048L * 128, 256L * 128, 0,
        G, 256, 8L * 65536, 65536, 0,
        128, 8, 1,
        nullptr, 0, nullptr, 0, 0, 0, nullptr, 0, 0, 0, nullptr, 0, 0, 0, 0, 0);

    // 6/7. two stages (= batch b): build Wbf then Y[t][d] += Wbf @ Xt^T
    for (int s = 0; s < 2; ++s) {
        k_wbuild<<<dim3(256, 256, 1), 256, 0, stream>>>(Acs, dtv, G, Wbf, s * 256);
        gemm_bt<<<dim3(1, 2, 256), 256, 0, stream>>>(
            Wbf, 256, 0, 32L * 65536, 65536,
            Xt + (size_t)s * 32 * 128 * 2048, 2048, 0, 256, 128L * 2048,
            Y + (size_t)s * 2048 * 4096, 4096, 0, 256L * 4096, 128,
            256, 8, 32,
            nullptr, 0,
            nullptr, 0, 0, 0,  nullptr, 0, 0, 0,  nullptr, 0, 0, 0,
            1, 1);
    }

    // 8. local states[p][n] = (Xt * cdec) @ Bt^T  (f32 out into d_out scratch)
    gemm_bt<<<dim3(1, 1, 512), 256, 0, stream>>>(
        Xt, 2048, 32L * 128 * 2048, 256, 128L * 2048,
        Bt, 2048, 128L * 2048, 256, 0,
        Sloc, 128, 8L * 32 * 16384, 32L * 16384, 16384,
        256, 8, 32,
        nullptr, 0,
        cdec, 8L * 32 * 256, 32L * 256, 256,
        nullptr, 0, 0, 0,  nullptr, 0, 0, 0,
        0, 0);

    // 9. chunk recurrence -> incoming states (bf16)
    k_recur<<<4096, 256, 0, stream>>>(Sloc, ctot, Sin);

    // 10. Y[t][d] += exp(Acs[l]) * (Cbf @ Sin^T)
    gemm_bt<<<dim3(1, 2, 512), 256, 0, stream>>>(
        Cbf, 128, 2048L * 128, 256L * 128, 0,
        Sin, 128, 8L * 32 * 16384, 32L * 16384, 16384,
        Y, 4096, 2048L * 4096, 256L * 4096, 128,
        128, 8, 32,
        nullptr, 0,
        nullptr, 0, 0, 0,  nullptr, 0, 0, 0,
        eacs, 8L * 32 * 256, 32L * 256, 256,
        1, 1);

    // 11. out_proj weight convert (into dead Wbf region)
    k_convert<<<2048, 256, 0, stream>>>(out_proj_w, W2bf, (long)DIMM * D_INNER, (long)DIMM * D_INNER);

    // 12. combine: *silu(z), RMSNorm -> Ybf (into dead Zxb region)
    k_combine<<<NTOK, 256, 0, stream>>>(Y, Zzb, norm_w, Ybf);

    // 13. GEMM2: out[4096][2048] = Ybf @ W2bf^T + out_proj_b  (f32 out)
    gemm_bt<<<dim3(16, 32, 1), 256, 0, stream>>>(
        Ybf, D_INNER, 0, 0, 0,
        W2bf, D_INNER, 0, 0, 0,
        out, DIMM, 0, 0, 0,
        D_INNER, 1, 1,
        out_proj_b, DIMM,
        nullptr, 0, 0, 0,  nullptr, 0, 0, 0,  nullptr, 0, 0, 0,
        0, 0);
}